// Round 10
// baseline (117.187 us; speedup 1.0000x reference)
//
#include <hip/hip_runtime.h>
#include <hip/hip_bf16.h>

#define NB   4
#define NC   256
#define NPOS 4096
#define NDQK 32

typedef __bf16 bf16x8  __attribute__((ext_vector_type(8)));
typedef float  f32x16  __attribute__((ext_vector_type(16)));

// V layout = PV-fragment image: [b][jt 128][cg 4][seg 4][hi 2][c' 32][e 8]
//   c = cg*64 + (seg>>1)*32 + c',  j = jt*32 + (seg&1)*16 + hi*8 + e.
// A wave (channel group cg) reads fragment seg of tile jt as ONE coalesced
// 1KB load: lane l -> elems (l*8..l*8+7) of segment  (l = hi*32 + c').

// =====================================================================
// Projection: Y[o][n] = sum_c W[o][c] x[c][n] + b[o], bf16 MFMA.
// Item = (b, g, nch64): g<4 -> V row-pairs (o0=g*64, o1=+32);
// g==4 -> Q (A0, pre-scaled log2e) and K (A1).
// =====================================================================
__global__ __launch_bounds__(256) void proj_kernel(
    const float* __restrict__ x,
    const float* __restrict__ Wq, const float* __restrict__ bq,
    const float* __restrict__ Wk, const float* __restrict__ bk,
    const float* __restrict__ Wv, const float* __restrict__ bv,
    __hip_bfloat16* __restrict__ Qb, __hip_bfloat16* __restrict__ Kb,
    __hip_bfloat16* __restrict__ Vb)
{
    const int t   = threadIdx.x;
    const int l   = t & 63;
    const int w   = t >> 6;
    const int hi  = l >> 5;
    const int col = l & 31;
    const int row = l & 31;

    const int item = blockIdx.x * 4 + w;     // 0..1279
    const int nch  = item & 63;              // 64-n chunk
    const int rest = item >> 6;              // 0..19
    const int g    = rest % 5;
    const int b    = rest / 5;

    const float *W0, *W1, *bs0, *bs1;
    int o0 = 0, o1 = 0;
    if (g < 4) {
        o0 = g * 64; o1 = g * 64 + 32;
        W0 = Wv + (size_t)o0 * NC; W1 = Wv + (size_t)o1 * NC;
        bs0 = bv + o0; bs1 = bv + o1;
    } else {
        W0 = Wq; W1 = Wk; bs0 = bq; bs1 = bk;
    }

    bf16x8 wf0[16], wf1[16];
    const float* Wr0 = W0 + (size_t)row * NC + 8 * hi;
    const float* Wr1 = W1 + (size_t)row * NC + 8 * hi;
    #pragma unroll
    for (int kk = 0; kk < 16; ++kk) {
        float4 a0 = *reinterpret_cast<const float4*>(Wr0 + kk * 16);
        float4 c0 = *reinterpret_cast<const float4*>(Wr0 + kk * 16 + 4);
        float4 a1 = *reinterpret_cast<const float4*>(Wr1 + kk * 16);
        float4 c1 = *reinterpret_cast<const float4*>(Wr1 + kk * 16 + 4);
        bf16x8 f0, f1;
        f0[0] = (__bf16)a0.x; f0[1] = (__bf16)a0.y; f0[2] = (__bf16)a0.z; f0[3] = (__bf16)a0.w;
        f0[4] = (__bf16)c0.x; f0[5] = (__bf16)c0.y; f0[6] = (__bf16)c0.z; f0[7] = (__bf16)c0.w;
        f1[0] = (__bf16)a1.x; f1[1] = (__bf16)a1.y; f1[2] = (__bf16)a1.z; f1[3] = (__bf16)a1.w;
        f1[4] = (__bf16)c1.x; f1[5] = (__bf16)c1.y; f1[6] = (__bf16)c1.z; f1[7] = (__bf16)c1.w;
        wf0[kk] = f0; wf1[kk] = f1;
    }

    #pragma unroll 1
    for (int tile = 0; tile < 2; ++tile) {
        const int n0 = nch * 64 + tile * 32;
        f32x16 acc0, acc1;
        #pragma unroll
        for (int r = 0; r < 16; ++r) { acc0[r] = 0.f; acc1[r] = 0.f; }

        const float* xcol = x + (size_t)b * NC * NPOS + n0 + col;
        #pragma unroll
        for (int kk = 0; kk < 16; ++kk) {
            bf16x8 bf;
            #pragma unroll
            for (int i = 0; i < 8; ++i)
                bf[i] = (__bf16)xcol[(size_t)(kk * 16 + 8 * hi + i) * NPOS];
            acc0 = __builtin_amdgcn_mfma_f32_32x32x16_bf16(wf0[kk], bf, acc0, 0, 0, 0);
            acc1 = __builtin_amdgcn_mfma_f32_32x32x16_bf16(wf1[kk], bf, acc1, 0, 0, 0);
        }

        if (g < 4) {
            __hip_bfloat16* vt = Vb + (size_t)b * NC * NPOS
                                    + (size_t)(n0 >> 5) * 8192 + (size_t)g * 2048
                                    + ((col >> 4) << 9) + (((col >> 3) & 1) << 8)
                                    + (col & 7);
            #pragma unroll
            for (int r = 0; r < 16; ++r) {
                const int orow = (r & 3) + 8 * (r >> 2) + 4 * hi;
                vt[orow * 8]        = __float2bfloat16(acc0[r] + bs0[orow]);
                vt[1024 + orow * 8] = __float2bfloat16(acc1[r] + bs1[orow]);
            }
        } else {
            #pragma unroll
            for (int r = 0; r < 16; ++r) {
                const int orow = (r & 3) + 8 * (r >> 2) + 4 * hi;
                const size_t nidx = (size_t)(b * NPOS) + n0 + col;
                Qb[nidx * NDQK + orow] =
                    __float2bfloat16((acc0[r] + bs0[orow]) * 1.44269504088896f);
                Kb[nidx * NDQK + orow] =
                    __float2bfloat16(acc1[r] + bs1[orow]);
            }
        }
    }
}

// =====================================================================
// Fused flash attention + residual, 32x32x16 MFMA, linear softmax
// (exp2, log2e folded into Q; no online max at |S|<~50).
//
// Block = 512 threads = 4 c-groups x 2 j-halves; each wave owns 32 q x
// 64 ch x 2048 j (64 tiles). Register-double-buffered V (frag-image
// layout, coalesced 1KB loads) + K. j-half partials combined through
// 32KB LDS + ONE __syncthreads at the end (softmax is linear, so O and
// l just add). Grid 512 -> 2 blocks/CU = 16 waves/CU (2x round 9 TLP).
// =====================================================================
__global__ __launch_bounds__(512, 4) void attn_kernel(
    const __hip_bfloat16* __restrict__ Qb,
    const __hip_bfloat16* __restrict__ Kb,
    const __hip_bfloat16* __restrict__ Vb,
    const float* __restrict__ x,
    const float* __restrict__ gamma,
    float* __restrict__ out)
{
    __shared__ float olds[4 * 32 * 64];          // 32 KB combine buffer
    __shared__ float lsum[32];
    const int t   = threadIdx.x;
    const int l   = t & 63;
    const int w   = t >> 6;                      // 0..7
    const int cg  = w & 3;                       // channel group (64 ch)
    const int jh  = w >> 2;                      // j-half
    const int hi  = l >> 5;
    const int q   = l & 31;
    const int bx  = blockIdx.x;
    const int b   = (bx >> 1) & 3;               // XCD-pair -> one batch
    const int qb  = ((bx >> 3) << 1) | (bx & 1); // 0..127
    const int q0  = qb * 32;
    const int c0w = cg * 64;

    const __bf16* Qp = reinterpret_cast<const __bf16*>(Qb) + (size_t)b * NPOS * NDQK;
    const __bf16* Kp = reinterpret_cast<const __bf16*>(Kb) + (size_t)b * NPOS * NDQK;
    const __bf16* Vp = reinterpret_cast<const __bf16*>(Vb) + (size_t)b * NC * NPOS;

    // swap bits 2<->3 of the A-row index so S lands exactly in PV B-frag order
    const int perm = (q & 0x13) | ((q & 4) << 1) | ((q & 8) >> 1);

    const bf16x8 qf0 = *reinterpret_cast<const bf16x8*>(Qp + (size_t)(q0 + q) * NDQK + 8 * hi);
    const bf16x8 qf1 = *reinterpret_cast<const bf16x8*>(Qp + (size_t)(q0 + q) * NDQK + 16 + 8 * hi);

    const __bf16* Kbase = Kp + (size_t)perm * NDQK + 8 * hi;
    const __bf16* vsrc  = Vp + (size_t)cg * 2048 + l * 8;

    f32x16 acc0, acc1;
    #pragma unroll
    for (int r = 0; r < 16; ++r) { acc0[r] = 0.f; acc1[r] = 0.f; }
    float lp = 0.f;

    // loop-invariant zero C-operand for QK^T (saves 16 v_mov per iter)
    f32x16 z16;
    #pragma unroll
    for (int r = 0; r < 16; ++r) z16[r] = 0.f;

    const int jt0 = jh * 64, jt1 = jt0 + 64;

    // register double-buffer: current tile's K + V fragments
    bf16x8 kc0 = *reinterpret_cast<const bf16x8*>(Kbase + (size_t)jt0 * 32 * NDQK);
    bf16x8 kc1 = *reinterpret_cast<const bf16x8*>(Kbase + (size_t)jt0 * 32 * NDQK + 16);
    bf16x8 vc0 = *reinterpret_cast<const bf16x8*>(vsrc + (size_t)jt0 * 8192);
    bf16x8 vc1 = *reinterpret_cast<const bf16x8*>(vsrc + (size_t)jt0 * 8192 + 512);
    bf16x8 vc2 = *reinterpret_cast<const bf16x8*>(vsrc + (size_t)jt0 * 8192 + 1024);
    bf16x8 vc3 = *reinterpret_cast<const bf16x8*>(vsrc + (size_t)jt0 * 8192 + 1536);

    #pragma unroll 2
    for (int jt = jt0; jt < jt1; ++jt) {
        bf16x8 kn0 = kc0, kn1 = kc1, vn0 = vc0, vn1 = vc1, vn2 = vc2, vn3 = vc3;
        if (jt < jt1 - 1) {
            const __bf16* kn = Kbase + (size_t)(jt + 1) * 32 * NDQK;
            const __bf16* vn = vsrc + (size_t)(jt + 1) * 8192;
            kn0 = *reinterpret_cast<const bf16x8*>(kn);
            kn1 = *reinterpret_cast<const bf16x8*>(kn + 16);
            vn0 = *reinterpret_cast<const bf16x8*>(vn);
            vn1 = *reinterpret_cast<const bf16x8*>(vn + 512);
            vn2 = *reinterpret_cast<const bf16x8*>(vn + 1024);
            vn3 = *reinterpret_cast<const bf16x8*>(vn + 1536);
        }

        f32x16 s = __builtin_amdgcn_mfma_f32_32x32x16_bf16(kc0, qf0, z16, 0, 0, 0);
        s = __builtin_amdgcn_mfma_f32_32x32x16_bf16(kc1, qf1, s, 0, 0, 0);

        float p[16];
        #pragma unroll
        for (int r = 0; r < 16; ++r) p[r] = __builtin_amdgcn_exp2f(s[r]);

        const float s0 = (p[0] + p[1]) + (p[2] + p[3]);
        const float s1 = (p[4] + p[5]) + (p[6] + p[7]);
        const float s2 = (p[8] + p[9]) + (p[10] + p[11]);
        const float s3 = (p[12] + p[13]) + (p[14] + p[15]);
        lp += (s0 + s1) + (s2 + s3);

        bf16x8 pa0, pa1;
        #pragma unroll
        for (int i = 0; i < 8; ++i) { pa0[i] = (__bf16)p[i]; pa1[i] = (__bf16)p[8 + i]; }

        acc0 = __builtin_amdgcn_mfma_f32_32x32x16_bf16(vc0, pa0, acc0, 0, 0, 0);
        acc0 = __builtin_amdgcn_mfma_f32_32x32x16_bf16(vc1, pa1, acc0, 0, 0, 0);
        acc1 = __builtin_amdgcn_mfma_f32_32x32x16_bf16(vc2, pa0, acc1, 0, 0, 0);
        acc1 = __builtin_amdgcn_mfma_f32_32x32x16_bf16(vc3, pa1, acc1, 0, 0, 0);

        kc0 = kn0; kc1 = kn1;
        vc0 = vn0; vc1 = vn1; vc2 = vn2; vc3 = vn3;
    }

    // per-q l partial for this j-half (both hi lanes hold the full 32-row sum)
    const float lt = lp + __shfl_xor(lp, 32);

    // ---- combine the two j-halves: jh0 -> LDS, one barrier, jh1 finishes
    if (jh == 0) {
        #pragma unroll
        for (int r = 0; r < 16; ++r) {
            olds[(cg * 32 + r) * 64 + l]      = acc0[r];
            olds[(cg * 32 + 16 + r) * 64 + l] = acc1[r];
        }
        if (cg == 0 && l < 32) lsum[q] = lt;
    }
    __syncthreads();
    if (jh == 1) {
        const float gl = gamma[0] / (lt + lsum[q]);
        #pragma unroll
        for (int r = 0; r < 16; ++r) {
            const int crow = (r & 3) + 8 * (r >> 2) + 4 * hi;
            const size_t g0 = ((size_t)(b * NC + c0w + crow)) * NPOS + q0 + q;
            const size_t g1 = g0 + (size_t)32 * NPOS;
            out[g0] = x[g0] + gl * (acc0[r] + olds[(cg * 32 + r) * 64 + l]);
            out[g1] = x[g1] + gl * (acc1[r] + olds[(cg * 32 + 16 + r) * 64 + l]);
        }
    }
}

extern "C" void kernel_launch(void* const* d_in, const int* in_sizes, int n_in,
                              void* d_out, int out_size, void* d_ws, size_t ws_size,
                              hipStream_t stream) {
    (void)in_sizes; (void)n_in; (void)out_size; (void)ws_size;
    const float* x     = (const float*)d_in[0];
    const float* Wq    = (const float*)d_in[1];
    const float* bq    = (const float*)d_in[2];
    const float* Wk    = (const float*)d_in[3];
    const float* bk    = (const float*)d_in[4];
    const float* Wv    = (const float*)d_in[5];
    const float* bv    = (const float*)d_in[6];
    const float* gamma = (const float*)d_in[7];
    float* out = (float*)d_out;

    char* ws = (char*)d_ws;
    __hip_bfloat16* Qb = (__hip_bfloat16*)(ws);                    // 1 MB
    __hip_bfloat16* Kb = (__hip_bfloat16*)(ws + (1u << 20));       // 1 MB
    __hip_bfloat16* Vb = (__hip_bfloat16*)(ws + (2u << 20));       // 8 MB (frag-image)

    proj_kernel<<<320, 256, 0, stream>>>(x, Wq, bq, Wk, bk, Wv, bv, Qb, Kb, Vb);
    attn_kernel<<<512, 512, 0, stream>>>(Qb, Kb, Vb, x, gamma, out);
}

// Round 11
// 111.178 us; speedup vs baseline: 1.0540x; 1.0540x over previous
//
#include <hip/hip_runtime.h>
#include <hip/hip_bf16.h>

#define NB   4
#define NC   256
#define NPOS 4096
#define NDQK 32

typedef __bf16 bf16x8  __attribute__((ext_vector_type(8)));
typedef float  f32x16  __attribute__((ext_vector_type(16)));
typedef unsigned int u32x4 __attribute__((ext_vector_type(4)));

// V layout = PV-fragment image: [b][jt 128][cg 4][seg 4][hi 2][c' 32][e 8]
//   c = cg*64 + (seg>>1)*32 + c',  j = jt*32 + (seg&1)*16 + hi*8 + e.
// A wave (channel group cg) reads fragment seg of tile jt as ONE coalesced
// 1KB load: lane l -> elems (l*8..l*8+7) of segment  (l = hi*32 + c').

// =====================================================================
// Projection: Y[o][n] = sum_c W[o][c] x[c][n] + b[o], bf16 MFMA.
// Item = (b, g, nch64): g<4 -> V row-pairs (o0=g*64, o1=+32);
// g==4 -> Q (A0, pre-scaled log2e) and K (A1).
// =====================================================================
__global__ __launch_bounds__(256) void proj_kernel(
    const float* __restrict__ x,
    const float* __restrict__ Wq, const float* __restrict__ bq,
    const float* __restrict__ Wk, const float* __restrict__ bk,
    const float* __restrict__ Wv, const float* __restrict__ bv,
    __hip_bfloat16* __restrict__ Qb, __hip_bfloat16* __restrict__ Kb,
    __hip_bfloat16* __restrict__ Vb)
{
    const int t   = threadIdx.x;
    const int l   = t & 63;
    const int w   = t >> 6;
    const int hi  = l >> 5;
    const int col = l & 31;
    const int row = l & 31;

    const int item = blockIdx.x * 4 + w;     // 0..1279
    const int nch  = item & 63;              // 64-n chunk
    const int rest = item >> 6;              // 0..19
    const int g    = rest % 5;
    const int b    = rest / 5;

    const float *W0, *W1, *bs0, *bs1;
    int o0 = 0, o1 = 0;
    if (g < 4) {
        o0 = g * 64; o1 = g * 64 + 32;
        W0 = Wv + (size_t)o0 * NC; W1 = Wv + (size_t)o1 * NC;
        bs0 = bv + o0; bs1 = bv + o1;
    } else {
        W0 = Wq; W1 = Wk; bs0 = bq; bs1 = bk;
    }

    bf16x8 wf0[16], wf1[16];
    const float* Wr0 = W0 + (size_t)row * NC + 8 * hi;
    const float* Wr1 = W1 + (size_t)row * NC + 8 * hi;
    #pragma unroll
    for (int kk = 0; kk < 16; ++kk) {
        float4 a0 = *reinterpret_cast<const float4*>(Wr0 + kk * 16);
        float4 c0 = *reinterpret_cast<const float4*>(Wr0 + kk * 16 + 4);
        float4 a1 = *reinterpret_cast<const float4*>(Wr1 + kk * 16);
        float4 c1 = *reinterpret_cast<const float4*>(Wr1 + kk * 16 + 4);
        bf16x8 f0, f1;
        f0[0] = (__bf16)a0.x; f0[1] = (__bf16)a0.y; f0[2] = (__bf16)a0.z; f0[3] = (__bf16)a0.w;
        f0[4] = (__bf16)c0.x; f0[5] = (__bf16)c0.y; f0[6] = (__bf16)c0.z; f0[7] = (__bf16)c0.w;
        f1[0] = (__bf16)a1.x; f1[1] = (__bf16)a1.y; f1[2] = (__bf16)a1.z; f1[3] = (__bf16)a1.w;
        f1[4] = (__bf16)c1.x; f1[5] = (__bf16)c1.y; f1[6] = (__bf16)c1.z; f1[7] = (__bf16)c1.w;
        wf0[kk] = f0; wf1[kk] = f1;
    }

    #pragma unroll 1
    for (int tile = 0; tile < 2; ++tile) {
        const int n0 = nch * 64 + tile * 32;
        f32x16 acc0, acc1;
        #pragma unroll
        for (int r = 0; r < 16; ++r) { acc0[r] = 0.f; acc1[r] = 0.f; }

        const float* xcol = x + (size_t)b * NC * NPOS + n0 + col;
        #pragma unroll
        for (int kk = 0; kk < 16; ++kk) {
            bf16x8 bf;
            #pragma unroll
            for (int i = 0; i < 8; ++i)
                bf[i] = (__bf16)xcol[(size_t)(kk * 16 + 8 * hi + i) * NPOS];
            acc0 = __builtin_amdgcn_mfma_f32_32x32x16_bf16(wf0[kk], bf, acc0, 0, 0, 0);
            acc1 = __builtin_amdgcn_mfma_f32_32x32x16_bf16(wf1[kk], bf, acc1, 0, 0, 0);
        }

        if (g < 4) {
            __hip_bfloat16* vt = Vb + (size_t)b * NC * NPOS
                                    + (size_t)(n0 >> 5) * 8192 + (size_t)g * 2048
                                    + ((col >> 4) << 9) + (((col >> 3) & 1) << 8)
                                    + (col & 7);
            #pragma unroll
            for (int r = 0; r < 16; ++r) {
                const int orow = (r & 3) + 8 * (r >> 2) + 4 * hi;
                vt[orow * 8]        = __float2bfloat16(acc0[r] + bs0[orow]);
                vt[1024 + orow * 8] = __float2bfloat16(acc1[r] + bs1[orow]);
            }
        } else {
            #pragma unroll
            for (int r = 0; r < 16; ++r) {
                const int orow = (r & 3) + 8 * (r >> 2) + 4 * hi;
                const size_t nidx = (size_t)(b * NPOS) + n0 + col;
                Qb[nidx * NDQK + orow] =
                    __float2bfloat16((acc0[r] + bs0[orow]) * 1.44269504088896f);
                Kb[nidx * NDQK + orow] =
                    __float2bfloat16(acc1[r] + bs1[orow]);
            }
        }
    }
}

// =====================================================================
// Fused flash attention + residual, 32x32x16 MFMA, linear softmax
// (exp2, log2e folded into Q; no online max at |S|<~50).
//
// Wave = 32 q x 64 ch, block = 4 waves (c-split), grid 512, no LDS.
// K/V register double-buffer is enforced with inline-asm
// global_load_dwordx4 into named A/B buffers (volatile asm cannot be
// sunk/rematerialized by the compiler — r9/r10's C++ prefetch was
// silently converted to load-at-use, exposing ~200cyc L2 latency per
// iteration; VGPR_Count=64 was the tell). Per iteration: issue next
// tile's 6 loads, sched_barrier, compute current, s_waitcnt vmcnt(0) +
// sched_barrier (rule #18). Manual 2x unroll alternates buffers.
// =====================================================================
__global__ __launch_bounds__(256, 2) void attn_kernel(
    const __hip_bfloat16* __restrict__ Qb,
    const __hip_bfloat16* __restrict__ Kb,
    const __hip_bfloat16* __restrict__ Vb,
    const float* __restrict__ x,
    const float* __restrict__ gamma,
    float* __restrict__ out)
{
    const int t   = threadIdx.x;
    const int l   = t & 63;
    const int w   = t >> 6;
    const int hi  = l >> 5;
    const int q   = l & 31;
    const int bx  = blockIdx.x;
    const int b   = (bx >> 1) & 3;               // XCD-pair -> one batch
    const int qb  = ((bx >> 3) << 1) | (bx & 1); // 0..127
    const int q0  = qb * 32;
    const int c0w = w * 64;

    const __bf16* Qp = reinterpret_cast<const __bf16*>(Qb) + (size_t)b * NPOS * NDQK;
    const __bf16* Kp = reinterpret_cast<const __bf16*>(Kb) + (size_t)b * NPOS * NDQK;
    const __bf16* Vp = reinterpret_cast<const __bf16*>(Vb) + (size_t)b * NC * NPOS;

    // swap bits 2<->3 of the A-row index so S lands exactly in PV B-frag order
    const int perm = (q & 0x13) | ((q & 4) << 1) | ((q & 8) >> 1);

    const bf16x8 qf0 = *reinterpret_cast<const bf16x8*>(Qp + (size_t)(q0 + q) * NDQK + 8 * hi);
    const bf16x8 qf1 = *reinterpret_cast<const bf16x8*>(Qp + (size_t)(q0 + q) * NDQK + 16 + 8 * hi);

    const __bf16* kp = Kp + (size_t)perm * NDQK + 8 * hi;  // tile stride 1024 elems
    const __bf16* vp = Vp + (size_t)w * 2048 + l * 8;      // tile stride 8192 elems

    // issue 6 loads of one tile: K frag pair (offsets 0,32B) + 4 V frags
    // (offsets 0,1024,2048,3072B). Early-clobber outputs; async results —
    // consumed only after the explicit vmcnt wait.
    #define LOADT(k0, k1, v0, v1, v2, v3, kptr, vptr)                      \
        asm volatile(                                                      \
            "global_load_dwordx4 %0, %6, off\n\t"                          \
            "global_load_dwordx4 %1, %6, off offset:32\n\t"                \
            "global_load_dwordx4 %2, %7, off\n\t"                          \
            "global_load_dwordx4 %3, %7, off offset:1024\n\t"              \
            "global_load_dwordx4 %4, %7, off offset:2048\n\t"              \
            "global_load_dwordx4 %5, %7, off offset:3072"                  \
            : "=&v"(k0), "=&v"(k1), "=&v"(v0), "=&v"(v1), "=&v"(v2), "=&v"(v3) \
            : "v"(kptr), "v"(vptr)                                         \
            : "memory")

    f32x16 acc0, acc1;
    #pragma unroll
    for (int r = 0; r < 16; ++r) { acc0[r] = 0.f; acc1[r] = 0.f; }
    float lp = 0.f;

    f32x16 z16;                                   // loop-invariant zero C-operand
    #pragma unroll
    for (int r = 0; r < 16; ++r) z16[r] = 0.f;

    auto compute = [&](u32x4 k0r, u32x4 k1r, u32x4 v0r, u32x4 v1r,
                       u32x4 v2r, u32x4 v3r) {
        const bf16x8 kc0 = __builtin_bit_cast(bf16x8, k0r);
        const bf16x8 kc1 = __builtin_bit_cast(bf16x8, k1r);
        const bf16x8 vc0 = __builtin_bit_cast(bf16x8, v0r);
        const bf16x8 vc1 = __builtin_bit_cast(bf16x8, v1r);
        const bf16x8 vc2 = __builtin_bit_cast(bf16x8, v2r);
        const bf16x8 vc3 = __builtin_bit_cast(bf16x8, v3r);

        f32x16 s = __builtin_amdgcn_mfma_f32_32x32x16_bf16(kc0, qf0, z16, 0, 0, 0);
        s = __builtin_amdgcn_mfma_f32_32x32x16_bf16(kc1, qf1, s, 0, 0, 0);

        float p[16];
        #pragma unroll
        for (int r = 0; r < 16; ++r) p[r] = __builtin_amdgcn_exp2f(s[r]);

        const float s0 = (p[0] + p[1]) + (p[2] + p[3]);
        const float s1 = (p[4] + p[5]) + (p[6] + p[7]);
        const float s2 = (p[8] + p[9]) + (p[10] + p[11]);
        const float s3 = (p[12] + p[13]) + (p[14] + p[15]);
        lp += (s0 + s1) + (s2 + s3);

        bf16x8 pa0, pa1;
        #pragma unroll
        for (int i = 0; i < 8; ++i) { pa0[i] = (__bf16)p[i]; pa1[i] = (__bf16)p[8 + i]; }

        acc0 = __builtin_amdgcn_mfma_f32_32x32x16_bf16(vc0, pa0, acc0, 0, 0, 0);
        acc0 = __builtin_amdgcn_mfma_f32_32x32x16_bf16(vc1, pa1, acc0, 0, 0, 0);
        acc1 = __builtin_amdgcn_mfma_f32_32x32x16_bf16(vc2, pa0, acc1, 0, 0, 0);
        acc1 = __builtin_amdgcn_mfma_f32_32x32x16_bf16(vc3, pa1, acc1, 0, 0, 0);
    };

    u32x4 ka0, ka1, va0, va1, va2, va3;
    u32x4 kb0, kb1, vb0, vb1, vb2, vb3;

    // prologue: tile 0 -> buffer A; pointers advance to tile 1
    LOADT(ka0, ka1, va0, va1, va2, va3, kp, vp);
    kp += 1024; vp += 8192;
    asm volatile("s_waitcnt vmcnt(0)" ::: "memory");
    __builtin_amdgcn_sched_barrier(0);

    #pragma unroll 1
    for (int jt = 0; jt < 128; jt += 2) {
        // even: prefetch tile jt+1 -> B, compute A (tile jt)
        LOADT(kb0, kb1, vb0, vb1, vb2, vb3, kp, vp);
        __builtin_amdgcn_sched_barrier(0);
        if (jt < 126) { kp += 1024; vp += 8192; }
        compute(ka0, ka1, va0, va1, va2, va3);
        asm volatile("s_waitcnt vmcnt(0)" ::: "memory");
        __builtin_amdgcn_sched_barrier(0);

        // odd: prefetch tile jt+2 -> A (dead reload of 127 on last pair),
        //      compute B (tile jt+1)
        LOADT(ka0, ka1, va0, va1, va2, va3, kp, vp);
        __builtin_amdgcn_sched_barrier(0);
        if (jt < 124) { kp += 1024; vp += 8192; }
        compute(kb0, kb1, vb0, vb1, vb2, vb3);
        asm volatile("s_waitcnt vmcnt(0)" ::: "memory");
        __builtin_amdgcn_sched_barrier(0);
    }
    #undef LOADT

    // epilogue: l is lane-local per q after one shfl; direct fused store
    const float lt = lp + __shfl_xor(lp, 32);
    const float gl = gamma[0] / lt;

    #pragma unroll
    for (int r = 0; r < 16; ++r) {
        const int crow = (r & 3) + 8 * (r >> 2) + 4 * hi;
        const size_t g0 = ((size_t)(b * NC + c0w + crow)) * NPOS + q0 + q;
        const size_t g1 = g0 + (size_t)32 * NPOS;
        out[g0] = x[g0] + gl * acc0[r];
        out[g1] = x[g1] + gl * acc1[r];
    }
}

extern "C" void kernel_launch(void* const* d_in, const int* in_sizes, int n_in,
                              void* d_out, int out_size, void* d_ws, size_t ws_size,
                              hipStream_t stream) {
    (void)in_sizes; (void)n_in; (void)out_size; (void)ws_size;
    const float* x     = (const float*)d_in[0];
    const float* Wq    = (const float*)d_in[1];
    const float* bq    = (const float*)d_in[2];
    const float* Wk    = (const float*)d_in[3];
    const float* bk    = (const float*)d_in[4];
    const float* Wv    = (const float*)d_in[5];
    const float* bv    = (const float*)d_in[6];
    const float* gamma = (const float*)d_in[7];
    float* out = (float*)d_out;

    char* ws = (char*)d_ws;
    __hip_bfloat16* Qb = (__hip_bfloat16*)(ws);                    // 1 MB
    __hip_bfloat16* Kb = (__hip_bfloat16*)(ws + (1u << 20));       // 1 MB
    __hip_bfloat16* Vb = (__hip_bfloat16*)(ws + (2u << 20));       // 8 MB (frag-image)

    proj_kernel<<<320, 256, 0, stream>>>(x, Wq, bq, Wk, bk, Wv, bv, Qb, Kb, Vb);
    attn_kernel<<<512, 256, 0, stream>>>(Qb, Kb, Vb, x, gamma, out);
}

// Round 12
// 96.873 us; speedup vs baseline: 1.2097x; 1.1477x over previous
//
#include <hip/hip_runtime.h>
#include <hip/hip_bf16.h>

#define NB   4
#define NC   256
#define NPOS 4096
#define NDQK 32

typedef __bf16 bf16x8  __attribute__((ext_vector_type(8)));
typedef float  f32x16  __attribute__((ext_vector_type(16)));
typedef unsigned int u32x4 __attribute__((ext_vector_type(4)));

// V layout = PV-fragment image: [b][jt 128][cg 4][seg 4][hi 2][c' 32][e 8]
//   c = cg*64 + (seg>>1)*32 + c',  j = jt*32 + (seg&1)*16 + hi*8 + e.

// =====================================================================
// Projection: Y[o][n] = sum_c W[o][c] x[c][n] + b[o], bf16 MFMA.
// Item = (b, g, nch64, th): one 32-n tile per wave-item (2560 items ->
// 2.5 waves/SIMD; r11's 2-tile loop halved parallelism).
// g<4 -> V row-pairs (o0=g*64, o1=+32); g==4 -> Q (log2e) and K.
// =====================================================================
__global__ __launch_bounds__(256) void proj_kernel(
    const float* __restrict__ x,
    const float* __restrict__ Wq, const float* __restrict__ bq,
    const float* __restrict__ Wk, const float* __restrict__ bk,
    const float* __restrict__ Wv, const float* __restrict__ bv,
    __hip_bfloat16* __restrict__ Qb, __hip_bfloat16* __restrict__ Kb,
    __hip_bfloat16* __restrict__ Vb)
{
    const int t   = threadIdx.x;
    const int l   = t & 63;
    const int w   = t >> 6;
    const int hi  = l >> 5;
    const int col = l & 31;
    const int row = l & 31;

    const int item = blockIdx.x * 4 + w;     // 0..2559
    const int th   = item & 1;               // tile half (32 n)
    const int nch  = (item >> 1) & 63;       // 64-n chunk
    const int rest = item >> 7;              // 0..19
    const int g    = rest % 5;
    const int b    = rest / 5;

    const float *W0, *W1, *bs0, *bs1;
    int o0 = 0, o1 = 0;
    if (g < 4) {
        o0 = g * 64; o1 = g * 64 + 32;
        W0 = Wv + (size_t)o0 * NC; W1 = Wv + (size_t)o1 * NC;
        bs0 = bv + o0; bs1 = bv + o1;
    } else {
        W0 = Wq; W1 = Wk; bs0 = bq; bs1 = bk;
    }

    bf16x8 wf0[16], wf1[16];
    const float* Wr0 = W0 + (size_t)row * NC + 8 * hi;
    const float* Wr1 = W1 + (size_t)row * NC + 8 * hi;
    #pragma unroll
    for (int kk = 0; kk < 16; ++kk) {
        float4 a0 = *reinterpret_cast<const float4*>(Wr0 + kk * 16);
        float4 c0 = *reinterpret_cast<const float4*>(Wr0 + kk * 16 + 4);
        float4 a1 = *reinterpret_cast<const float4*>(Wr1 + kk * 16);
        float4 c1 = *reinterpret_cast<const float4*>(Wr1 + kk * 16 + 4);
        bf16x8 f0, f1;
        f0[0] = (__bf16)a0.x; f0[1] = (__bf16)a0.y; f0[2] = (__bf16)a0.z; f0[3] = (__bf16)a0.w;
        f0[4] = (__bf16)c0.x; f0[5] = (__bf16)c0.y; f0[6] = (__bf16)c0.z; f0[7] = (__bf16)c0.w;
        f1[0] = (__bf16)a1.x; f1[1] = (__bf16)a1.y; f1[2] = (__bf16)a1.z; f1[3] = (__bf16)a1.w;
        f1[4] = (__bf16)c1.x; f1[5] = (__bf16)c1.y; f1[6] = (__bf16)c1.z; f1[7] = (__bf16)c1.w;
        wf0[kk] = f0; wf1[kk] = f1;
    }

    const int n0 = nch * 64 + th * 32;
    f32x16 acc0, acc1;
    #pragma unroll
    for (int r = 0; r < 16; ++r) { acc0[r] = 0.f; acc1[r] = 0.f; }

    const float* xcol = x + (size_t)b * NC * NPOS + n0 + col;
    #pragma unroll
    for (int kk = 0; kk < 16; ++kk) {
        bf16x8 bf;
        #pragma unroll
        for (int i = 0; i < 8; ++i)
            bf[i] = (__bf16)xcol[(size_t)(kk * 16 + 8 * hi + i) * NPOS];
        acc0 = __builtin_amdgcn_mfma_f32_32x32x16_bf16(wf0[kk], bf, acc0, 0, 0, 0);
        acc1 = __builtin_amdgcn_mfma_f32_32x32x16_bf16(wf1[kk], bf, acc1, 0, 0, 0);
    }

    if (g < 4) {
        __hip_bfloat16* vt = Vb + (size_t)b * NC * NPOS
                                + (size_t)(n0 >> 5) * 8192 + (size_t)g * 2048
                                + ((col >> 4) << 9) + (((col >> 3) & 1) << 8)
                                + (col & 7);
        #pragma unroll
        for (int r = 0; r < 16; ++r) {
            const int orow = (r & 3) + 8 * (r >> 2) + 4 * hi;
            vt[orow * 8]        = __float2bfloat16(acc0[r] + bs0[orow]);
            vt[1024 + orow * 8] = __float2bfloat16(acc1[r] + bs1[orow]);
        }
    } else {
        #pragma unroll
        for (int r = 0; r < 16; ++r) {
            const int orow = (r & 3) + 8 * (r >> 2) + 4 * hi;
            const size_t nidx = (size_t)(b * NPOS) + n0 + col;
            Qb[nidx * NDQK + orow] =
                __float2bfloat16((acc0[r] + bs0[orow]) * 1.44269504088896f);
            Kb[nidx * NDQK + orow] =
                __float2bfloat16(acc1[r] + bs1[orow]);
        }
    }
}

// =====================================================================
// Fused flash attention + residual, 32x32x16 MFMA, linear softmax
// (exp2, log2e folded into Q; no online max at |S|<~50).
//
// Wave = 64 q x 64 ch (2x arithmetic intensity vs r11: each 6KB K/V
// load round serves 64 queries -> L2 traffic halves to ~0.75GB).
// Block = 512 threads = 4 cg x 2 j-halves; grid 256 (1 block/CU,
// XCD-pair -> one batch). Inline-asm A/B register double-buffer (r11).
// j-halves combined linearly via 64KB LDS + one __syncthreads.
// =====================================================================
__global__ __launch_bounds__(512, 2) void attn_kernel(
    const __hip_bfloat16* __restrict__ Qb,
    const __hip_bfloat16* __restrict__ Kb,
    const __hip_bfloat16* __restrict__ Vb,
    const float* __restrict__ x,
    const float* __restrict__ gamma,
    float* __restrict__ out)
{
    __shared__ float olds[NC * 64];              // 64 KB combine buffer
    __shared__ float lsum[64];
    const int t   = threadIdx.x;
    const int l   = t & 63;
    const int w   = t >> 6;                      // 0..7
    const int cg  = w & 3;
    const int jh  = w >> 2;
    const int hi  = l >> 5;
    const int q   = l & 31;
    const int bx  = blockIdx.x;
    const int b   = (bx >> 1) & 3;               // XCD-pair -> one batch
    const int qt  = ((bx >> 3) << 1) | (bx & 1); // 0..63
    const int q0  = qt * 64;
    const int c0w = cg * 64;

    const __bf16* Qp = reinterpret_cast<const __bf16*>(Qb) + (size_t)b * NPOS * NDQK;
    const __bf16* Kp = reinterpret_cast<const __bf16*>(Kb) + (size_t)b * NPOS * NDQK;
    const __bf16* Vp = reinterpret_cast<const __bf16*>(Vb) + (size_t)b * NC * NPOS;

    // swap bits 2<->3 of the A-row index so S lands exactly in PV B-frag order
    const int perm = (q & 0x13) | ((q & 4) << 1) | ((q & 8) >> 1);

    const bf16x8 qf00 = *reinterpret_cast<const bf16x8*>(Qp + (size_t)(q0 + q) * NDQK + 8 * hi);
    const bf16x8 qf01 = *reinterpret_cast<const bf16x8*>(Qp + (size_t)(q0 + q) * NDQK + 16 + 8 * hi);
    const bf16x8 qf10 = *reinterpret_cast<const bf16x8*>(Qp + (size_t)(q0 + 32 + q) * NDQK + 8 * hi);
    const bf16x8 qf11 = *reinterpret_cast<const bf16x8*>(Qp + (size_t)(q0 + 32 + q) * NDQK + 16 + 8 * hi);

    const int jt0 = jh * 64;
    const __bf16* kp = Kp + (size_t)perm * NDQK + 8 * hi + (size_t)jt0 * 1024;
    const __bf16* vp = Vp + (size_t)cg * 2048 + l * 8 + (size_t)jt0 * 8192;

    #define LOADT(k0, k1, v0, v1, v2, v3, kptr, vptr)                      \
        asm volatile(                                                      \
            "global_load_dwordx4 %0, %6, off\n\t"                          \
            "global_load_dwordx4 %1, %6, off offset:32\n\t"                \
            "global_load_dwordx4 %2, %7, off\n\t"                          \
            "global_load_dwordx4 %3, %7, off offset:1024\n\t"              \
            "global_load_dwordx4 %4, %7, off offset:2048\n\t"              \
            "global_load_dwordx4 %5, %7, off offset:3072"                  \
            : "=&v"(k0), "=&v"(k1), "=&v"(v0), "=&v"(v1), "=&v"(v2), "=&v"(v3) \
            : "v"(kptr), "v"(vptr)                                         \
            : "memory")

    f32x16 acc00, acc01, acc10, acc11;
    #pragma unroll
    for (int r = 0; r < 16; ++r) { acc00[r] = 0.f; acc01[r] = 0.f; acc10[r] = 0.f; acc11[r] = 0.f; }
    float lp0 = 0.f, lp1 = 0.f;

    f32x16 z16;
    #pragma unroll
    for (int r = 0; r < 16; ++r) z16[r] = 0.f;

    auto compute = [&](u32x4 k0r, u32x4 k1r, u32x4 v0r, u32x4 v1r,
                       u32x4 v2r, u32x4 v3r) {
        const bf16x8 kc0 = __builtin_bit_cast(bf16x8, k0r);
        const bf16x8 kc1 = __builtin_bit_cast(bf16x8, k1r);
        const bf16x8 vc0 = __builtin_bit_cast(bf16x8, v0r);
        const bf16x8 vc1 = __builtin_bit_cast(bf16x8, v1r);
        const bf16x8 vc2 = __builtin_bit_cast(bf16x8, v2r);
        const bf16x8 vc3 = __builtin_bit_cast(bf16x8, v3r);

        f32x16 s0 = __builtin_amdgcn_mfma_f32_32x32x16_bf16(kc0, qf00, z16, 0, 0, 0);
        s0 = __builtin_amdgcn_mfma_f32_32x32x16_bf16(kc1, qf01, s0, 0, 0, 0);
        f32x16 s1 = __builtin_amdgcn_mfma_f32_32x32x16_bf16(kc0, qf10, z16, 0, 0, 0);
        s1 = __builtin_amdgcn_mfma_f32_32x32x16_bf16(kc1, qf11, s1, 0, 0, 0);

        float p0[16], p1[16];
        #pragma unroll
        for (int r = 0; r < 16; ++r) p0[r] = __builtin_amdgcn_exp2f(s0[r]);
        #pragma unroll
        for (int r = 0; r < 16; ++r) p1[r] = __builtin_amdgcn_exp2f(s1[r]);

        lp0 += (((p0[0] + p0[1]) + (p0[2] + p0[3])) + ((p0[4] + p0[5]) + (p0[6] + p0[7])))
             + (((p0[8] + p0[9]) + (p0[10] + p0[11])) + ((p0[12] + p0[13]) + (p0[14] + p0[15])));
        lp1 += (((p1[0] + p1[1]) + (p1[2] + p1[3])) + ((p1[4] + p1[5]) + (p1[6] + p1[7])))
             + (((p1[8] + p1[9]) + (p1[10] + p1[11])) + ((p1[12] + p1[13]) + (p1[14] + p1[15])));

        bf16x8 pa00, pa01, pa10, pa11;
        #pragma unroll
        for (int i = 0; i < 8; ++i) {
            pa00[i] = (__bf16)p0[i]; pa01[i] = (__bf16)p0[8 + i];
            pa10[i] = (__bf16)p1[i]; pa11[i] = (__bf16)p1[8 + i];
        }

        acc00 = __builtin_amdgcn_mfma_f32_32x32x16_bf16(vc0, pa00, acc00, 0, 0, 0);
        acc00 = __builtin_amdgcn_mfma_f32_32x32x16_bf16(vc1, pa01, acc00, 0, 0, 0);
        acc01 = __builtin_amdgcn_mfma_f32_32x32x16_bf16(vc2, pa00, acc01, 0, 0, 0);
        acc01 = __builtin_amdgcn_mfma_f32_32x32x16_bf16(vc3, pa01, acc01, 0, 0, 0);
        acc10 = __builtin_amdgcn_mfma_f32_32x32x16_bf16(vc0, pa10, acc10, 0, 0, 0);
        acc10 = __builtin_amdgcn_mfma_f32_32x32x16_bf16(vc1, pa11, acc10, 0, 0, 0);
        acc11 = __builtin_amdgcn_mfma_f32_32x32x16_bf16(vc2, pa10, acc11, 0, 0, 0);
        acc11 = __builtin_amdgcn_mfma_f32_32x32x16_bf16(vc3, pa11, acc11, 0, 0, 0);
    };

    u32x4 ka0, ka1, va0, va1, va2, va3;
    u32x4 kb0, kb1, vb0, vb1, vb2, vb3;

    LOADT(ka0, ka1, va0, va1, va2, va3, kp, vp);
    kp += 1024; vp += 8192;
    asm volatile("s_waitcnt vmcnt(0)" ::: "memory");
    __builtin_amdgcn_sched_barrier(0);

    #pragma unroll 1
    for (int i = 0; i < 64; i += 2) {
        LOADT(kb0, kb1, vb0, vb1, vb2, vb3, kp, vp);
        __builtin_amdgcn_sched_barrier(0);
        if (i < 62) { kp += 1024; vp += 8192; }
        compute(ka0, ka1, va0, va1, va2, va3);
        asm volatile("s_waitcnt vmcnt(0)" ::: "memory");
        __builtin_amdgcn_sched_barrier(0);

        LOADT(ka0, ka1, va0, va1, va2, va3, kp, vp);
        __builtin_amdgcn_sched_barrier(0);
        if (i < 60) { kp += 1024; vp += 8192; }
        compute(kb0, kb1, vb0, vb1, vb2, vb3);
        asm volatile("s_waitcnt vmcnt(0)" ::: "memory");
        __builtin_amdgcn_sched_barrier(0);
    }
    #undef LOADT

    const float lt0 = lp0 + __shfl_xor(lp0, 32);
    const float lt1 = lp1 + __shfl_xor(lp1, 32);

    // ---- combine the two j-halves: jh0 -> LDS, one barrier, jh1 finishes
    if (jh == 0) {
        #pragma unroll
        for (int r = 0; r < 16; ++r) {
            const int crow = (r & 3) + 8 * (r >> 2) + 4 * hi;
            olds[(c0w + crow) * 64 + q]           = acc00[r];
            olds[(c0w + 32 + crow) * 64 + q]      = acc01[r];
            olds[(c0w + crow) * 64 + 32 + q]      = acc10[r];
            olds[(c0w + 32 + crow) * 64 + 32 + q] = acc11[r];
        }
        if (cg == 0) { lsum[q + 32 * hi] = hi ? lt1 : lt0; }
    }
    __syncthreads();
    if (jh == 1) {
        const float gm  = gamma[0];
        const float gl0 = gm / (lt0 + lsum[q]);
        const float gl1 = gm / (lt1 + lsum[32 + q]);
        #pragma unroll
        for (int r = 0; r < 16; ++r) {
            const int crow = (r & 3) + 8 * (r >> 2) + 4 * hi;
            const size_t g00 = ((size_t)(b * NC + c0w + crow)) * NPOS + q0 + q;
            const size_t g01 = g00 + (size_t)32 * NPOS;
            out[g00]      = x[g00]      + gl0 * (acc00[r] + olds[(c0w + crow) * 64 + q]);
            out[g01]      = x[g01]      + gl0 * (acc01[r] + olds[(c0w + 32 + crow) * 64 + q]);
            out[g00 + 32] = x[g00 + 32] + gl1 * (acc10[r] + olds[(c0w + crow) * 64 + 32 + q]);
            out[g01 + 32] = x[g01 + 32] + gl1 * (acc11[r] + olds[(c0w + 32 + crow) * 64 + 32 + q]);
        }
    }
}

extern "C" void kernel_launch(void* const* d_in, const int* in_sizes, int n_in,
                              void* d_out, int out_size, void* d_ws, size_t ws_size,
                              hipStream_t stream) {
    (void)in_sizes; (void)n_in; (void)out_size; (void)ws_size;
    const float* x     = (const float*)d_in[0];
    const float* Wq    = (const float*)d_in[1];
    const float* bq    = (const float*)d_in[2];
    const float* Wk    = (const float*)d_in[3];
    const float* bk    = (const float*)d_in[4];
    const float* Wv    = (const float*)d_in[5];
    const float* bv    = (const float*)d_in[6];
    const float* gamma = (const float*)d_in[7];
    float* out = (float*)d_out;

    char* ws = (char*)d_ws;
    __hip_bfloat16* Qb = (__hip_bfloat16*)(ws);                    // 1 MB
    __hip_bfloat16* Kb = (__hip_bfloat16*)(ws + (1u << 20));       // 1 MB
    __hip_bfloat16* Vb = (__hip_bfloat16*)(ws + (2u << 20));       // 8 MB (frag-image)

    proj_kernel<<<640, 256, 0, stream>>>(x, Wq, bq, Wk, bk, Wv, bv, Qb, Kb, Vb);
    attn_kernel<<<256, 512, 0, stream>>>(Qb, Kb, Vb, x, gamma, out);
}

// Round 15
// 96.376 us; speedup vs baseline: 1.2159x; 1.0052x over previous
//
#include <hip/hip_runtime.h>
#include <hip/hip_bf16.h>

#define NB   4
#define NC   256
#define NPOS 4096
#define NDQK 32

typedef __bf16 bf16x8  __attribute__((ext_vector_type(8)));
typedef float  f32x16  __attribute__((ext_vector_type(16)));
typedef unsigned int u32x4 __attribute__((ext_vector_type(4)));

// V layout = PV-fragment image: [b][jt 128][cg 4][seg 4][hi 2][c' 32][e 8]
//   c = cg*64 + (seg>>1)*32 + c',  j = jt*32 + (seg&1)*16 + hi*8 + e.

// =====================================================================
// Projection: Y[o][n] = sum_c W[o][c] x[c][n] + b[o], bf16 MFMA.
// Item = (b, g, nch64, th): one 32-n tile per wave-item.
// g<4 -> V row-pairs (o0=g*64, o1=+32); g==4 -> Q (log2e) and K.
// =====================================================================
__global__ __launch_bounds__(256) void proj_kernel(
    const float* __restrict__ x,
    const float* __restrict__ Wq, const float* __restrict__ bq,
    const float* __restrict__ Wk, const float* __restrict__ bk,
    const float* __restrict__ Wv, const float* __restrict__ bv,
    __hip_bfloat16* __restrict__ Qb, __hip_bfloat16* __restrict__ Kb,
    __hip_bfloat16* __restrict__ Vb)
{
    const int t   = threadIdx.x;
    const int l   = t & 63;
    const int w   = t >> 6;
    const int hi  = l >> 5;
    const int col = l & 31;
    const int row = l & 31;

    const int item = blockIdx.x * 4 + w;     // 0..2559
    const int th   = item & 1;               // tile half (32 n)
    const int nch  = (item >> 1) & 63;       // 64-n chunk
    const int rest = item >> 7;              // 0..19
    const int g    = rest % 5;
    const int b    = rest / 5;

    const float *W0, *W1, *bs0, *bs1;
    int o0 = 0, o1 = 0;
    if (g < 4) {
        o0 = g * 64; o1 = g * 64 + 32;
        W0 = Wv + (size_t)o0 * NC; W1 = Wv + (size_t)o1 * NC;
        bs0 = bv + o0; bs1 = bv + o1;
    } else {
        W0 = Wq; W1 = Wk; bs0 = bq; bs1 = bk;
    }

    bf16x8 wf0[16], wf1[16];
    const float* Wr0 = W0 + (size_t)row * NC + 8 * hi;
    const float* Wr1 = W1 + (size_t)row * NC + 8 * hi;
    #pragma unroll
    for (int kk = 0; kk < 16; ++kk) {
        float4 a0 = *reinterpret_cast<const float4*>(Wr0 + kk * 16);
        float4 c0 = *reinterpret_cast<const float4*>(Wr0 + kk * 16 + 4);
        float4 a1 = *reinterpret_cast<const float4*>(Wr1 + kk * 16);
        float4 c1 = *reinterpret_cast<const float4*>(Wr1 + kk * 16 + 4);
        bf16x8 f0, f1;
        f0[0] = (__bf16)a0.x; f0[1] = (__bf16)a0.y; f0[2] = (__bf16)a0.z; f0[3] = (__bf16)a0.w;
        f0[4] = (__bf16)c0.x; f0[5] = (__bf16)c0.y; f0[6] = (__bf16)c0.z; f0[7] = (__bf16)c0.w;
        f1[0] = (__bf16)a1.x; f1[1] = (__bf16)a1.y; f1[2] = (__bf16)a1.z; f1[3] = (__bf16)a1.w;
        f1[4] = (__bf16)c1.x; f1[5] = (__bf16)c1.y; f1[6] = (__bf16)c1.z; f1[7] = (__bf16)c1.w;
        wf0[kk] = f0; wf1[kk] = f1;
    }

    const int n0 = nch * 64 + th * 32;
    f32x16 acc0, acc1;
    #pragma unroll
    for (int r = 0; r < 16; ++r) { acc0[r] = 0.f; acc1[r] = 0.f; }

    const float* xcol = x + (size_t)b * NC * NPOS + n0 + col;
    #pragma unroll
    for (int kk = 0; kk < 16; ++kk) {
        bf16x8 bf;
        #pragma unroll
        for (int i = 0; i < 8; ++i)
            bf[i] = (__bf16)xcol[(size_t)(kk * 16 + 8 * hi + i) * NPOS];
        acc0 = __builtin_amdgcn_mfma_f32_32x32x16_bf16(wf0[kk], bf, acc0, 0, 0, 0);
        acc1 = __builtin_amdgcn_mfma_f32_32x32x16_bf16(wf1[kk], bf, acc1, 0, 0, 0);
    }

    if (g < 4) {
        __hip_bfloat16* vt = Vb + (size_t)b * NC * NPOS
                                + (size_t)(n0 >> 5) * 8192 + (size_t)g * 2048
                                + ((col >> 4) << 9) + (((col >> 3) & 1) << 8)
                                + (col & 7);
        #pragma unroll
        for (int r = 0; r < 16; ++r) {
            const int orow = (r & 3) + 8 * (r >> 2) + 4 * hi;
            vt[orow * 8]        = __float2bfloat16(acc0[r] + bs0[orow]);
            vt[1024 + orow * 8] = __float2bfloat16(acc1[r] + bs1[orow]);
        }
    } else {
        #pragma unroll
        for (int r = 0; r < 16; ++r) {
            const int orow = (r & 3) + 8 * (r >> 2) + 4 * hi;
            const size_t nidx = (size_t)(b * NPOS) + n0 + col;
            Qb[nidx * NDQK + orow] =
                __float2bfloat16((acc0[r] + bs0[orow]) * 1.44269504088896f);
            Kb[nidx * NDQK + orow] =
                __float2bfloat16(acc1[r] + bs1[orow]);
        }
    }
}

// =====================================================================
// Fused flash attention + residual, 32x32x16 MFMA, linear softmax
// (exp2, log2e folded into Q; no online max at |S|<~50).
//
// Wave = 64 q x 64 ch. Block = 256 threads = 4 j-quarter waves of ONE
// channel group; grid 1024 (4 b x 64 qt x 4 cg). launch_bounds(256,2)
// (proven value; r13/r14's min=4 crashed — suspect VGPR-cap regalloc
// with the inline asm). HW may co-schedule up to 4 blocks/CU (LDS 33KB
// x4 = 132KB, VGPR ~112 -> 4/SIMD).
// Combine = single-writer 2-buffer tree: P1 jq0->bufA, jq1->bufB (+all
// waves write own lsum slot); P2 jq2+=bufA, jq3+=bufB; P3 all 4 waves
// read bufA+bufB and store cooperatively. Two barriers, none in loop.
// Inline-asm A/B register double-buffer (r11); tail advance fixed
// (both conditions i<30 — r12..14 never loaded the last tile).
// =====================================================================
__global__ __launch_bounds__(256, 2) void attn_kernel(
    const __hip_bfloat16* __restrict__ Qb,
    const __hip_bfloat16* __restrict__ Kb,
    const __hip_bfloat16* __restrict__ Vb,
    const float* __restrict__ x,
    const float* __restrict__ gamma,
    float* __restrict__ out)
{
    __shared__ float olds[2 * 64 * 64];          // 32 KB: bufA | bufB
    __shared__ float lsum[4 * 64];               // per-jq l partials
    const int t   = threadIdx.x;
    const int l   = t & 63;
    const int jq  = t >> 6;                      // j-quarter 0..3
    const int hi  = l >> 5;
    const int q   = l & 31;
    const int bx  = blockIdx.x;
    const int b   = (bx >> 1) & 3;               // XCD-pair -> one batch
    const int id  = ((bx >> 3) << 1) | (bx & 1); // 0..255
    const int qt  = id >> 2;                     // 0..63
    const int cg  = id & 3;
    const int q0  = qt * 64;
    const int c0  = cg * 64;

    const __bf16* Qp = reinterpret_cast<const __bf16*>(Qb) + (size_t)b * NPOS * NDQK;
    const __bf16* Kp = reinterpret_cast<const __bf16*>(Kb) + (size_t)b * NPOS * NDQK;
    const __bf16* Vp = reinterpret_cast<const __bf16*>(Vb) + (size_t)b * NC * NPOS;

    // swap bits 2<->3 of the A-row index so S lands exactly in PV B-frag order
    const int perm = (q & 0x13) | ((q & 4) << 1) | ((q & 8) >> 1);

    const bf16x8 qf00 = *reinterpret_cast<const bf16x8*>(Qp + (size_t)(q0 + q) * NDQK + 8 * hi);
    const bf16x8 qf01 = *reinterpret_cast<const bf16x8*>(Qp + (size_t)(q0 + q) * NDQK + 16 + 8 * hi);
    const bf16x8 qf10 = *reinterpret_cast<const bf16x8*>(Qp + (size_t)(q0 + 32 + q) * NDQK + 8 * hi);
    const bf16x8 qf11 = *reinterpret_cast<const bf16x8*>(Qp + (size_t)(q0 + 32 + q) * NDQK + 16 + 8 * hi);

    const int jt0 = jq * 32;
    const __bf16* kp = Kp + (size_t)perm * NDQK + 8 * hi + (size_t)jt0 * 1024;
    const __bf16* vp = Vp + (size_t)cg * 2048 + l * 8 + (size_t)jt0 * 8192;

    #define LOADT(k0, k1, v0, v1, v2, v3, kptr, vptr)                      \
        asm volatile(                                                      \
            "global_load_dwordx4 %0, %6, off\n\t"                          \
            "global_load_dwordx4 %1, %6, off offset:32\n\t"                \
            "global_load_dwordx4 %2, %7, off\n\t"                          \
            "global_load_dwordx4 %3, %7, off offset:1024\n\t"              \
            "global_load_dwordx4 %4, %7, off offset:2048\n\t"              \
            "global_load_dwordx4 %5, %7, off offset:3072"                  \
            : "=&v"(k0), "=&v"(k1), "=&v"(v0), "=&v"(v1), "=&v"(v2), "=&v"(v3) \
            : "v"(kptr), "v"(vptr)                                         \
            : "memory")

    f32x16 acc00, acc01, acc10, acc11;
    #pragma unroll
    for (int r = 0; r < 16; ++r) { acc00[r] = 0.f; acc01[r] = 0.f; acc10[r] = 0.f; acc11[r] = 0.f; }
    float lp0 = 0.f, lp1 = 0.f;

    f32x16 z16;
    #pragma unroll
    for (int r = 0; r < 16; ++r) z16[r] = 0.f;

    auto compute = [&](u32x4 k0r, u32x4 k1r, u32x4 v0r, u32x4 v1r,
                       u32x4 v2r, u32x4 v3r) {
        const bf16x8 kc0 = __builtin_bit_cast(bf16x8, k0r);
        const bf16x8 kc1 = __builtin_bit_cast(bf16x8, k1r);
        const bf16x8 vc0 = __builtin_bit_cast(bf16x8, v0r);
        const bf16x8 vc1 = __builtin_bit_cast(bf16x8, v1r);
        const bf16x8 vc2 = __builtin_bit_cast(bf16x8, v2r);
        const bf16x8 vc3 = __builtin_bit_cast(bf16x8, v3r);

        f32x16 s0 = __builtin_amdgcn_mfma_f32_32x32x16_bf16(kc0, qf00, z16, 0, 0, 0);
        s0 = __builtin_amdgcn_mfma_f32_32x32x16_bf16(kc1, qf01, s0, 0, 0, 0);
        f32x16 s1 = __builtin_amdgcn_mfma_f32_32x32x16_bf16(kc0, qf10, z16, 0, 0, 0);
        s1 = __builtin_amdgcn_mfma_f32_32x32x16_bf16(kc1, qf11, s1, 0, 0, 0);

        float p0[16], p1[16];
        #pragma unroll
        for (int r = 0; r < 16; ++r) p0[r] = __builtin_amdgcn_exp2f(s0[r]);
        #pragma unroll
        for (int r = 0; r < 16; ++r) p1[r] = __builtin_amdgcn_exp2f(s1[r]);

        lp0 += (((p0[0] + p0[1]) + (p0[2] + p0[3])) + ((p0[4] + p0[5]) + (p0[6] + p0[7])))
             + (((p0[8] + p0[9]) + (p0[10] + p0[11])) + ((p0[12] + p0[13]) + (p0[14] + p0[15])));
        lp1 += (((p1[0] + p1[1]) + (p1[2] + p1[3])) + ((p1[4] + p1[5]) + (p1[6] + p1[7])))
             + (((p1[8] + p1[9]) + (p1[10] + p1[11])) + ((p1[12] + p1[13]) + (p1[14] + p1[15])));

        bf16x8 pa00, pa01, pa10, pa11;
        #pragma unroll
        for (int i = 0; i < 8; ++i) {
            pa00[i] = (__bf16)p0[i]; pa01[i] = (__bf16)p0[8 + i];
            pa10[i] = (__bf16)p1[i]; pa11[i] = (__bf16)p1[8 + i];
        }

        acc00 = __builtin_amdgcn_mfma_f32_32x32x16_bf16(vc0, pa00, acc00, 0, 0, 0);
        acc00 = __builtin_amdgcn_mfma_f32_32x32x16_bf16(vc1, pa01, acc00, 0, 0, 0);
        acc01 = __builtin_amdgcn_mfma_f32_32x32x16_bf16(vc2, pa00, acc01, 0, 0, 0);
        acc01 = __builtin_amdgcn_mfma_f32_32x32x16_bf16(vc3, pa01, acc01, 0, 0, 0);
        acc10 = __builtin_amdgcn_mfma_f32_32x32x16_bf16(vc0, pa10, acc10, 0, 0, 0);
        acc10 = __builtin_amdgcn_mfma_f32_32x32x16_bf16(vc1, pa11, acc10, 0, 0, 0);
        acc11 = __builtin_amdgcn_mfma_f32_32x32x16_bf16(vc2, pa10, acc11, 0, 0, 0);
        acc11 = __builtin_amdgcn_mfma_f32_32x32x16_bf16(vc3, pa11, acc11, 0, 0, 0);
    };

    u32x4 ka0, ka1, va0, va1, va2, va3;
    u32x4 kb0, kb1, vb0, vb1, vb2, vb3;

    // prologue: tile 0 -> A; invariant: before pair i, ptr = tile i+1
    LOADT(ka0, ka1, va0, va1, va2, va3, kp, vp);
    kp += 1024; vp += 8192;
    asm volatile("s_waitcnt vmcnt(0)" ::: "memory");
    __builtin_amdgcn_sched_barrier(0);

    #pragma unroll 1
    for (int i = 0; i < 32; i += 2) {
        LOADT(kb0, kb1, vb0, vb1, vb2, vb3, kp, vp);   // tile i+1 -> B
        __builtin_amdgcn_sched_barrier(0);
        if (i < 30) { kp += 1024; vp += 8192; }        // -> tile i+2
        compute(ka0, ka1, va0, va1, va2, va3);         // tile i
        asm volatile("s_waitcnt vmcnt(0)" ::: "memory");
        __builtin_amdgcn_sched_barrier(0);

        LOADT(ka0, ka1, va0, va1, va2, va3, kp, vp);   // tile i+2 -> A
        __builtin_amdgcn_sched_barrier(0);
        if (i < 30) { kp += 1024; vp += 8192; }        // -> tile i+3
        compute(kb0, kb1, vb0, vb1, vb2, vb3);         // tile i+1
        asm volatile("s_waitcnt vmcnt(0)" ::: "memory");
        __builtin_amdgcn_sched_barrier(0);
    }
    #undef LOADT

    const float lt0 = lp0 + __shfl_xor(lp0, 32);       // l-total, queries q0+q
    const float lt1 = lp1 + __shfl_xor(lp1, 32);       // l-total, queries q0+32+q

    // all waves publish their l partial (distinct slots)
    lsum[jq * 64 + 32 * hi + q] = hi ? lt1 : lt0;

    // ---- phase 1: jq0 -> bufA, jq1 -> bufB
    float* buf = olds + (jq & 1) * 4096;
    if (jq < 2) {
        #pragma unroll
        for (int r = 0; r < 16; ++r) {
            const int crow = (r & 3) + 8 * (r >> 2) + 4 * hi;
            buf[(crow) * 64 + q]           = acc00[r];
            buf[(32 + crow) * 64 + q]      = acc01[r];
            buf[(crow) * 64 + 32 + q]      = acc10[r];
            buf[(32 + crow) * 64 + 32 + q] = acc11[r];
        }
    }
    __syncthreads();
    // ---- phase 2: jq2 += bufA, jq3 += bufB
    if (jq >= 2) {
        #pragma unroll
        for (int r = 0; r < 16; ++r) {
            const int crow = (r & 3) + 8 * (r >> 2) + 4 * hi;
            buf[(crow) * 64 + q]           += acc00[r];
            buf[(32 + crow) * 64 + q]      += acc01[r];
            buf[(crow) * 64 + 32 + q]      += acc10[r];
            buf[(32 + crow) * 64 + 32 + q] += acc11[r];
        }
    }
    __syncthreads();
    // ---- phase 3: all 4 waves read bufA+bufB, store 16 rows each
    {
        const float gm   = gamma[0];
        const float ltot = lsum[l] + lsum[64 + l] + lsum[128 + l] + lsum[192 + l];
        const float gl   = gm / ltot;
        #pragma unroll
        for (int rr = 0; rr < 16; ++rr) {
            const int c = jq * 16 + rr;
            const float v = olds[c * 64 + l] + olds[4096 + c * 64 + l];
            const size_t gi = ((size_t)(b * NC + c0 + c)) * NPOS + q0 + l;
            out[gi] = x[gi] + gl * v;
        }
    }
}

extern "C" void kernel_launch(void* const* d_in, const int* in_sizes, int n_in,
                              void* d_out, int out_size, void* d_ws, size_t ws_size,
                              hipStream_t stream) {
    (void)in_sizes; (void)n_in; (void)out_size; (void)ws_size;
    const float* x     = (const float*)d_in[0];
    const float* Wq    = (const float*)d_in[1];
    const float* bq    = (const float*)d_in[2];
    const float* Wk    = (const float*)d_in[3];
    const float* bk    = (const float*)d_in[4];
    const float* Wv    = (const float*)d_in[5];
    const float* bv    = (const float*)d_in[6];
    const float* gamma = (const float*)d_in[7];
    float* out = (float*)d_out;

    char* ws = (char*)d_ws;
    __hip_bfloat16* Qb = (__hip_bfloat16*)(ws);                    // 1 MB
    __hip_bfloat16* Kb = (__hip_bfloat16*)(ws + (1u << 20));       // 1 MB
    __hip_bfloat16* Vb = (__hip_bfloat16*)(ws + (2u << 20));       // 8 MB (frag-image)

    proj_kernel<<<640, 256, 0, stream>>>(x, Wq, bq, Wk, bk, Wv, bv, Qb, Kb, Vb);
    attn_kernel<<<1024, 256, 0, stream>>>(Qb, Kb, Vb, x, gamma, out);
}

// Round 16
// 95.817 us; speedup vs baseline: 1.2230x; 1.0058x over previous
//
#include <hip/hip_runtime.h>
#include <hip/hip_bf16.h>

#define NB   4
#define NC   256
#define NPOS 4096
#define NDQK 32

typedef __bf16 bf16x8  __attribute__((ext_vector_type(8)));
typedef float  f32x16  __attribute__((ext_vector_type(16)));
typedef unsigned int u32x4 __attribute__((ext_vector_type(4)));

// V layout = PV-fragment image: [b][jt 128][cg 4][seg 4][hi 2][c' 32][e 8]
//   c = cg*64 + (seg>>1)*32 + c',  j = jt*32 + (seg&1)*16 + hi*8 + e.

// =====================================================================
// Projection: Y[o][n] = sum_c W[o][c] x[c][n] + b[o], bf16 MFMA.
// Item = (b, g, nch64, th): one 32-n tile per wave-item.
// g<4 -> V row-pairs (o0=g*64, o1=+32); g==4 -> Q (log2e) and K.
// =====================================================================
__global__ __launch_bounds__(256) void proj_kernel(
    const float* __restrict__ x,
    const float* __restrict__ Wq, const float* __restrict__ bq,
    const float* __restrict__ Wk, const float* __restrict__ bk,
    const float* __restrict__ Wv, const float* __restrict__ bv,
    __hip_bfloat16* __restrict__ Qb, __hip_bfloat16* __restrict__ Kb,
    __hip_bfloat16* __restrict__ Vb)
{
    const int t   = threadIdx.x;
    const int l   = t & 63;
    const int w   = t >> 6;
    const int hi  = l >> 5;
    const int col = l & 31;
    const int row = l & 31;

    const int item = blockIdx.x * 4 + w;     // 0..2559
    const int th   = item & 1;               // tile half (32 n)
    const int nch  = (item >> 1) & 63;       // 64-n chunk
    const int rest = item >> 7;              // 0..19
    const int g    = rest % 5;
    const int b    = rest / 5;

    const float *W0, *W1, *bs0, *bs1;
    int o0 = 0, o1 = 0;
    if (g < 4) {
        o0 = g * 64; o1 = g * 64 + 32;
        W0 = Wv + (size_t)o0 * NC; W1 = Wv + (size_t)o1 * NC;
        bs0 = bv + o0; bs1 = bv + o1;
    } else {
        W0 = Wq; W1 = Wk; bs0 = bq; bs1 = bk;
    }

    bf16x8 wf0[16], wf1[16];
    const float* Wr0 = W0 + (size_t)row * NC + 8 * hi;
    const float* Wr1 = W1 + (size_t)row * NC + 8 * hi;
    #pragma unroll
    for (int kk = 0; kk < 16; ++kk) {
        float4 a0 = *reinterpret_cast<const float4*>(Wr0 + kk * 16);
        float4 c0 = *reinterpret_cast<const float4*>(Wr0 + kk * 16 + 4);
        float4 a1 = *reinterpret_cast<const float4*>(Wr1 + kk * 16);
        float4 c1 = *reinterpret_cast<const float4*>(Wr1 + kk * 16 + 4);
        bf16x8 f0, f1;
        f0[0] = (__bf16)a0.x; f0[1] = (__bf16)a0.y; f0[2] = (__bf16)a0.z; f0[3] = (__bf16)a0.w;
        f0[4] = (__bf16)c0.x; f0[5] = (__bf16)c0.y; f0[6] = (__bf16)c0.z; f0[7] = (__bf16)c0.w;
        f1[0] = (__bf16)a1.x; f1[1] = (__bf16)a1.y; f1[2] = (__bf16)a1.z; f1[3] = (__bf16)a1.w;
        f1[4] = (__bf16)c1.x; f1[5] = (__bf16)c1.y; f1[6] = (__bf16)c1.z; f1[7] = (__bf16)c1.w;
        wf0[kk] = f0; wf1[kk] = f1;
    }

    const int n0 = nch * 64 + th * 32;
    f32x16 acc0, acc1;
    #pragma unroll
    for (int r = 0; r < 16; ++r) { acc0[r] = 0.f; acc1[r] = 0.f; }

    const float* xcol = x + (size_t)b * NC * NPOS + n0 + col;
    #pragma unroll
    for (int kk = 0; kk < 16; ++kk) {
        bf16x8 bf;
        #pragma unroll
        for (int i = 0; i < 8; ++i)
            bf[i] = (__bf16)xcol[(size_t)(kk * 16 + 8 * hi + i) * NPOS];
        acc0 = __builtin_amdgcn_mfma_f32_32x32x16_bf16(wf0[kk], bf, acc0, 0, 0, 0);
        acc1 = __builtin_amdgcn_mfma_f32_32x32x16_bf16(wf1[kk], bf, acc1, 0, 0, 0);
    }

    if (g < 4) {
        __hip_bfloat16* vt = Vb + (size_t)b * NC * NPOS
                                + (size_t)(n0 >> 5) * 8192 + (size_t)g * 2048
                                + ((col >> 4) << 9) + (((col >> 3) & 1) << 8)
                                + (col & 7);
        #pragma unroll
        for (int r = 0; r < 16; ++r) {
            const int orow = (r & 3) + 8 * (r >> 2) + 4 * hi;
            vt[orow * 8]        = __float2bfloat16(acc0[r] + bs0[orow]);
            vt[1024 + orow * 8] = __float2bfloat16(acc1[r] + bs1[orow]);
        }
    } else {
        #pragma unroll
        for (int r = 0; r < 16; ++r) {
            const int orow = (r & 3) + 8 * (r >> 2) + 4 * hi;
            const size_t nidx = (size_t)(b * NPOS) + n0 + col;
            Qb[nidx * NDQK + orow] =
                __float2bfloat16((acc0[r] + bs0[orow]) * 1.44269504088896f);
            Kb[nidx * NDQK + orow] =
                __float2bfloat16(acc1[r] + bs1[orow]);
        }
    }
}

// =====================================================================
// Fused flash attention + residual, 32x32x16 MFMA, linear softmax
// (exp2, log2e folded into Q; no online max at |S|<~50).
//
// Wave = 64 q x 64 ch. Block = 256 threads = 4 j-quarter waves of ONE
// channel group; grid 1024 (4 b x 64 qt x 4 cg).
// r15 diagnosis: total regs = 112 arch VGPR + 64 acc = 176/wave ->
// 2 waves/SIMD cap (512/176) — the r12..r15 timing invariance. This
// round's single change: the hoisted 16-reg zero C-operand (z16) is
// re-materialized per tile inside the loop with an anti-hoist
// asm volatile("":"+v"(z)) — 16 v_mov/tile (~8% more VALU) buys
// total regs 176->160 <= 170 -> 3 waves/SIMD (+50% TLP).
// Everything else identical to the passing r15.
// =====================================================================
__global__ __launch_bounds__(256, 2) void attn_kernel(
    const __hip_bfloat16* __restrict__ Qb,
    const __hip_bfloat16* __restrict__ Kb,
    const __hip_bfloat16* __restrict__ Vb,
    const float* __restrict__ x,
    const float* __restrict__ gamma,
    float* __restrict__ out)
{
    __shared__ float olds[2 * 64 * 64];          // 32 KB: bufA | bufB
    __shared__ float lsum[4 * 64];               // per-jq l partials
    const int t   = threadIdx.x;
    const int l   = t & 63;
    const int jq  = t >> 6;                      // j-quarter 0..3
    const int hi  = l >> 5;
    const int q   = l & 31;
    const int bx  = blockIdx.x;
    const int b   = (bx >> 1) & 3;               // XCD-pair -> one batch
    const int id  = ((bx >> 3) << 1) | (bx & 1); // 0..255
    const int qt  = id >> 2;                     // 0..63
    const int cg  = id & 3;
    const int q0  = qt * 64;
    const int c0  = cg * 64;

    const __bf16* Qp = reinterpret_cast<const __bf16*>(Qb) + (size_t)b * NPOS * NDQK;
    const __bf16* Kp = reinterpret_cast<const __bf16*>(Kb) + (size_t)b * NPOS * NDQK;
    const __bf16* Vp = reinterpret_cast<const __bf16*>(Vb) + (size_t)b * NC * NPOS;

    // swap bits 2<->3 of the A-row index so S lands exactly in PV B-frag order
    const int perm = (q & 0x13) | ((q & 4) << 1) | ((q & 8) >> 1);

    const bf16x8 qf00 = *reinterpret_cast<const bf16x8*>(Qp + (size_t)(q0 + q) * NDQK + 8 * hi);
    const bf16x8 qf01 = *reinterpret_cast<const bf16x8*>(Qp + (size_t)(q0 + q) * NDQK + 16 + 8 * hi);
    const bf16x8 qf10 = *reinterpret_cast<const bf16x8*>(Qp + (size_t)(q0 + 32 + q) * NDQK + 8 * hi);
    const bf16x8 qf11 = *reinterpret_cast<const bf16x8*>(Qp + (size_t)(q0 + 32 + q) * NDQK + 16 + 8 * hi);

    const int jt0 = jq * 32;
    const __bf16* kp = Kp + (size_t)perm * NDQK + 8 * hi + (size_t)jt0 * 1024;
    const __bf16* vp = Vp + (size_t)cg * 2048 + l * 8 + (size_t)jt0 * 8192;

    #define LOADT(k0, k1, v0, v1, v2, v3, kptr, vptr)                      \
        asm volatile(                                                      \
            "global_load_dwordx4 %0, %6, off\n\t"                          \
            "global_load_dwordx4 %1, %6, off offset:32\n\t"                \
            "global_load_dwordx4 %2, %7, off\n\t"                          \
            "global_load_dwordx4 %3, %7, off offset:1024\n\t"              \
            "global_load_dwordx4 %4, %7, off offset:2048\n\t"              \
            "global_load_dwordx4 %5, %7, off offset:3072"                  \
            : "=&v"(k0), "=&v"(k1), "=&v"(v0), "=&v"(v1), "=&v"(v2), "=&v"(v3) \
            : "v"(kptr), "v"(vptr)                                         \
            : "memory")

    f32x16 acc00, acc01, acc10, acc11;
    #pragma unroll
    for (int r = 0; r < 16; ++r) { acc00[r] = 0.f; acc01[r] = 0.f; acc10[r] = 0.f; acc11[r] = 0.f; }
    float lp0 = 0.f, lp1 = 0.f;

    auto compute = [&](u32x4 k0r, u32x4 k1r, u32x4 v0r, u32x4 v1r,
                       u32x4 v2r, u32x4 v3r) {
        const bf16x8 kc0 = __builtin_bit_cast(bf16x8, k0r);
        const bf16x8 kc1 = __builtin_bit_cast(bf16x8, k1r);
        const bf16x8 vc0 = __builtin_bit_cast(bf16x8, v0r);
        const bf16x8 vc1 = __builtin_bit_cast(bf16x8, v1r);
        const bf16x8 vc2 = __builtin_bit_cast(bf16x8, v2r);
        const bf16x8 vc3 = __builtin_bit_cast(bf16x8, v3r);

        // per-tile zero C-operand; asm volatile defeats LICM so these 16
        // v_movs do NOT become 16 loop-persistent registers (reg 176->160:
        // crosses the 3-waves/SIMD threshold at 512/170)
        f32x16 z;
        #pragma unroll
        for (int r = 0; r < 16; ++r) z[r] = 0.f;
        asm volatile("" : "+v"(z));

        f32x16 s0 = __builtin_amdgcn_mfma_f32_32x32x16_bf16(kc0, qf00, z, 0, 0, 0);
        s0 = __builtin_amdgcn_mfma_f32_32x32x16_bf16(kc1, qf01, s0, 0, 0, 0);
        f32x16 s1 = __builtin_amdgcn_mfma_f32_32x32x16_bf16(kc0, qf10, z, 0, 0, 0);
        s1 = __builtin_amdgcn_mfma_f32_32x32x16_bf16(kc1, qf11, s1, 0, 0, 0);

        float p0[16], p1[16];
        #pragma unroll
        for (int r = 0; r < 16; ++r) p0[r] = __builtin_amdgcn_exp2f(s0[r]);
        #pragma unroll
        for (int r = 0; r < 16; ++r) p1[r] = __builtin_amdgcn_exp2f(s1[r]);

        lp0 += (((p0[0] + p0[1]) + (p0[2] + p0[3])) + ((p0[4] + p0[5]) + (p0[6] + p0[7])))
             + (((p0[8] + p0[9]) + (p0[10] + p0[11])) + ((p0[12] + p0[13]) + (p0[14] + p0[15])));
        lp1 += (((p1[0] + p1[1]) + (p1[2] + p1[3])) + ((p1[4] + p1[5]) + (p1[6] + p1[7])))
             + (((p1[8] + p1[9]) + (p1[10] + p1[11])) + ((p1[12] + p1[13]) + (p1[14] + p1[15])));

        bf16x8 pa00, pa01, pa10, pa11;
        #pragma unroll
        for (int i = 0; i < 8; ++i) {
            pa00[i] = (__bf16)p0[i]; pa01[i] = (__bf16)p0[8 + i];
            pa10[i] = (__bf16)p1[i]; pa11[i] = (__bf16)p1[8 + i];
        }

        acc00 = __builtin_amdgcn_mfma_f32_32x32x16_bf16(vc0, pa00, acc00, 0, 0, 0);
        acc00 = __builtin_amdgcn_mfma_f32_32x32x16_bf16(vc1, pa01, acc00, 0, 0, 0);
        acc01 = __builtin_amdgcn_mfma_f32_32x32x16_bf16(vc2, pa00, acc01, 0, 0, 0);
        acc01 = __builtin_amdgcn_mfma_f32_32x32x16_bf16(vc3, pa01, acc01, 0, 0, 0);
        acc10 = __builtin_amdgcn_mfma_f32_32x32x16_bf16(vc0, pa10, acc10, 0, 0, 0);
        acc10 = __builtin_amdgcn_mfma_f32_32x32x16_bf16(vc1, pa11, acc10, 0, 0, 0);
        acc11 = __builtin_amdgcn_mfma_f32_32x32x16_bf16(vc2, pa10, acc11, 0, 0, 0);
        acc11 = __builtin_amdgcn_mfma_f32_32x32x16_bf16(vc3, pa11, acc11, 0, 0, 0);
    };

    u32x4 ka0, ka1, va0, va1, va2, va3;
    u32x4 kb0, kb1, vb0, vb1, vb2, vb3;

    // prologue: tile 0 -> A; invariant: before pair i, ptr = tile i+1
    LOADT(ka0, ka1, va0, va1, va2, va3, kp, vp);
    kp += 1024; vp += 8192;
    asm volatile("s_waitcnt vmcnt(0)" ::: "memory");
    __builtin_amdgcn_sched_barrier(0);

    #pragma unroll 1
    for (int i = 0; i < 32; i += 2) {
        LOADT(kb0, kb1, vb0, vb1, vb2, vb3, kp, vp);   // tile i+1 -> B
        __builtin_amdgcn_sched_barrier(0);
        if (i < 30) { kp += 1024; vp += 8192; }        // -> tile i+2
        compute(ka0, ka1, va0, va1, va2, va3);         // tile i
        asm volatile("s_waitcnt vmcnt(0)" ::: "memory");
        __builtin_amdgcn_sched_barrier(0);

        LOADT(ka0, ka1, va0, va1, va2, va3, kp, vp);   // tile i+2 -> A
        __builtin_amdgcn_sched_barrier(0);
        if (i < 30) { kp += 1024; vp += 8192; }        // -> tile i+3
        compute(kb0, kb1, vb0, vb1, vb2, vb3);         // tile i+1
        asm volatile("s_waitcnt vmcnt(0)" ::: "memory");
        __builtin_amdgcn_sched_barrier(0);
    }
    #undef LOADT

    const float lt0 = lp0 + __shfl_xor(lp0, 32);       // l-total, queries q0+q
    const float lt1 = lp1 + __shfl_xor(lp1, 32);       // l-total, queries q0+32+q

    // all waves publish their l partial (distinct slots)
    lsum[jq * 64 + 32 * hi + q] = hi ? lt1 : lt0;

    // ---- phase 1: jq0 -> bufA, jq1 -> bufB
    float* buf = olds + (jq & 1) * 4096;
    if (jq < 2) {
        #pragma unroll
        for (int r = 0; r < 16; ++r) {
            const int crow = (r & 3) + 8 * (r >> 2) + 4 * hi;
            buf[(crow) * 64 + q]           = acc00[r];
            buf[(32 + crow) * 64 + q]      = acc01[r];
            buf[(crow) * 64 + 32 + q]      = acc10[r];
            buf[(32 + crow) * 64 + 32 + q] = acc11[r];
        }
    }
    __syncthreads();
    // ---- phase 2: jq2 += bufA, jq3 += bufB
    if (jq >= 2) {
        #pragma unroll
        for (int r = 0; r < 16; ++r) {
            const int crow = (r & 3) + 8 * (r >> 2) + 4 * hi;
            buf[(crow) * 64 + q]           += acc00[r];
            buf[(32 + crow) * 64 + q]      += acc01[r];
            buf[(crow) * 64 + 32 + q]      += acc10[r];
            buf[(32 + crow) * 64 + 32 + q] += acc11[r];
        }
    }
    __syncthreads();
    // ---- phase 3: all 4 waves read bufA+bufB, store 16 rows each
    {
        const float gm   = gamma[0];
        const float ltot = lsum[l] + lsum[64 + l] + lsum[128 + l] + lsum[192 + l];
        const float gl   = gm / ltot;
        #pragma unroll
        for (int rr = 0; rr < 16; ++rr) {
            const int c = jq * 16 + rr;
            const float v = olds[c * 64 + l] + olds[4096 + c * 64 + l];
            const size_t gi = ((size_t)(b * NC + c0 + c)) * NPOS + q0 + l;
            out[gi] = x[gi] + gl * v;
        }
    }
}

extern "C" void kernel_launch(void* const* d_in, const int* in_sizes, int n_in,
                              void* d_out, int out_size, void* d_ws, size_t ws_size,
                              hipStream_t stream) {
    (void)in_sizes; (void)n_in; (void)out_size; (void)ws_size;
    const float* x     = (const float*)d_in[0];
    const float* Wq    = (const float*)d_in[1];
    const float* bq    = (const float*)d_in[2];
    const float* Wk    = (const float*)d_in[3];
    const float* bk    = (const float*)d_in[4];
    const float* Wv    = (const float*)d_in[5];
    const float* bv    = (const float*)d_in[6];
    const float* gamma = (const float*)d_in[7];
    float* out = (float*)d_out;

    char* ws = (char*)d_ws;
    __hip_bfloat16* Qb = (__hip_bfloat16*)(ws);                    // 1 MB
    __hip_bfloat16* Kb = (__hip_bfloat16*)(ws + (1u << 20));       // 1 MB
    __hip_bfloat16* Vb = (__hip_bfloat16*)(ws + (2u << 20));       // 8 MB (frag-image)

    proj_kernel<<<640, 256, 0, stream>>>(x, Wq, bq, Wk, bk, Wv, bv, Qb, Kb, Vb);
    attn_kernel<<<1024, 256, 0, stream>>>(Qb, Kb, Vb, x, gamma, out);
}

// Round 18
// 91.966 us; speedup vs baseline: 1.2742x; 1.0419x over previous
//
#include <hip/hip_runtime.h>
#include <hip/hip_bf16.h>

#define NB   4
#define NC   256
#define NPOS 4096
#define NDQK 32

typedef __bf16 bf16x8  __attribute__((ext_vector_type(8)));
typedef float  f32x16  __attribute__((ext_vector_type(16)));

typedef __attribute__((address_space(3))) char*       lds_ptr_t;
typedef const __attribute__((address_space(1))) char* glb_ptr_t;

// V image: [b][jt 128][cg 4][seg 4][hi 2][c' 32][e 8]
//   c = cg*64 + (seg>>1)*32 + c',  j = jt*32 + (seg&1)*16 + hi*8 + e.
// K image: [b][jt 128][seg 2][hi 2][row 32][e 8], row PRE-PERMUTED
//   (perm = swap bits 2<->3 of j-within-tile; involution, baked at proj).
// Both: a tile is contiguous; DMA lane l reads bytes l*16, LDS holds the
// exact fragment image -> reads at lane*16B, conflict-free by construction.

// =====================================================================
// Projection: Y[o][n] = sum_c W[o][c] x[c][n] + b[o], bf16 MFMA.
// =====================================================================
__global__ __launch_bounds__(256) void proj_kernel(
    const float* __restrict__ x,
    const float* __restrict__ Wq, const float* __restrict__ bq,
    const float* __restrict__ Wk, const float* __restrict__ bk,
    const float* __restrict__ Wv, const float* __restrict__ bv,
    __hip_bfloat16* __restrict__ Qb, __hip_bfloat16* __restrict__ Kb,
    __hip_bfloat16* __restrict__ Vb)
{
    const int t   = threadIdx.x;
    const int l   = t & 63;
    const int w   = t >> 6;
    const int hi  = l >> 5;
    const int col = l & 31;
    const int row = l & 31;

    const int item = blockIdx.x * 4 + w;     // 0..2559
    const int th   = item & 1;
    const int nch  = (item >> 1) & 63;
    const int rest = item >> 7;              // 0..19
    const int g    = rest % 5;
    const int b    = rest / 5;

    const float *W0, *W1, *bs0, *bs1;
    int o0 = 0, o1 = 0;
    if (g < 4) {
        o0 = g * 64; o1 = g * 64 + 32;
        W0 = Wv + (size_t)o0 * NC; W1 = Wv + (size_t)o1 * NC;
        bs0 = bv + o0; bs1 = bv + o1;
    } else {
        W0 = Wq; W1 = Wk; bs0 = bq; bs1 = bk;
    }

    bf16x8 wf0[16], wf1[16];
    const float* Wr0 = W0 + (size_t)row * NC + 8 * hi;
    const float* Wr1 = W1 + (size_t)row * NC + 8 * hi;
    #pragma unroll
    for (int kk = 0; kk < 16; ++kk) {
        float4 a0 = *reinterpret_cast<const float4*>(Wr0 + kk * 16);
        float4 c0 = *reinterpret_cast<const float4*>(Wr0 + kk * 16 + 4);
        float4 a1 = *reinterpret_cast<const float4*>(Wr1 + kk * 16);
        float4 c1 = *reinterpret_cast<const float4*>(Wr1 + kk * 16 + 4);
        bf16x8 f0, f1;
        f0[0] = (__bf16)a0.x; f0[1] = (__bf16)a0.y; f0[2] = (__bf16)a0.z; f0[3] = (__bf16)a0.w;
        f0[4] = (__bf16)c0.x; f0[5] = (__bf16)c0.y; f0[6] = (__bf16)c0.z; f0[7] = (__bf16)c0.w;
        f1[0] = (__bf16)a1.x; f1[1] = (__bf16)a1.y; f1[2] = (__bf16)a1.z; f1[3] = (__bf16)a1.w;
        f1[4] = (__bf16)c1.x; f1[5] = (__bf16)c1.y; f1[6] = (__bf16)c1.z; f1[7] = (__bf16)c1.w;
        wf0[kk] = f0; wf1[kk] = f1;
    }

    const int n0 = nch * 64 + th * 32;
    f32x16 acc0, acc1;
    #pragma unroll
    for (int r = 0; r < 16; ++r) { acc0[r] = 0.f; acc1[r] = 0.f; }

    const float* xcol = x + (size_t)b * NC * NPOS + n0 + col;
    #pragma unroll
    for (int kk = 0; kk < 16; ++kk) {
        bf16x8 bf;
        #pragma unroll
        for (int i = 0; i < 8; ++i)
            bf[i] = (__bf16)xcol[(size_t)(kk * 16 + 8 * hi + i) * NPOS];
        acc0 = __builtin_amdgcn_mfma_f32_32x32x16_bf16(wf0[kk], bf, acc0, 0, 0, 0);
        acc1 = __builtin_amdgcn_mfma_f32_32x32x16_bf16(wf1[kk], bf, acc1, 0, 0, 0);
    }

    if (g < 4) {
        __hip_bfloat16* vt = Vb + (size_t)b * NC * NPOS
                                + (size_t)(n0 >> 5) * 8192 + (size_t)g * 2048
                                + ((col >> 4) << 9) + (((col >> 3) & 1) << 8)
                                + (col & 7);
        #pragma unroll
        for (int r = 0; r < 16; ++r) {
            const int orow = (r & 3) + 8 * (r >> 2) + 4 * hi;
            vt[orow * 8]        = __float2bfloat16(acc0[r] + bs0[orow]);
            vt[1024 + orow * 8] = __float2bfloat16(acc1[r] + bs1[orow]);
        }
    } else {
        // Q: row-major [n][dqk], pre-scaled by log2e
        #pragma unroll
        for (int r = 0; r < 16; ++r) {
            const int orow = (r & 3) + 8 * (r >> 2) + 4 * hi;
            Qb[((size_t)(b * NPOS) + n0 + col) * NDQK + orow] =
                __float2bfloat16((acc0[r] + bs0[orow]) * 1.44269504088896f);
        }
        // K: fragment image, row pre-permuted
        const int prow = (col & 0x13) | ((col & 4) << 1) | ((col & 8) >> 1);
        __hip_bfloat16* kt = Kb + (size_t)b * (NPOS * 32)
                                + (size_t)(n0 >> 5) * 1024 + prow * 8;
        #pragma unroll
        for (int r = 0; r < 16; ++r) {
            const int orow = (r & 3) + 8 * (r >> 2) + 4 * hi;
            kt[(orow >> 4) * 512 + ((orow >> 3) & 1) * 256 + (orow & 7)] =
                __float2bfloat16(acc1[r] + bs1[orow]);
        }
    }
}

// =====================================================================
// Fused flash attention + residual, de-duplicated softmax, ALL loads
// via global_load_lds (DMA has no output VGPRs -> immune to the r17
// regalloc-copy race that NaN'd counted-vmcnt register prefetch).
//
// Block = 4 waves = 4 cg (all 256 ch of one (b,qt)); grid 256. Per
// round of 4 j-tiles: wave w does QK+softmax for tile 4r+w only (K
// from LDS, perm baked into layout), shares P via LDS; then PVs all 4
// tiles for its own cg from double-buffered V LDS tiles. Counted
// vmcnt ledger: prologue 6; per round 8/8/8/10 -> waits 4,4,4,4,6
// (last round 0). lgkmcnt(0) before every LDS-buffer reuse. Raw
// s_barrier (never drains vmcnt) + sched_barrier(0) fences.
// =====================================================================
__global__ __launch_bounds__(256, 1) void attn_kernel(
    const __hip_bfloat16* __restrict__ Qb,
    const __hip_bfloat16* __restrict__ Kb,
    const __hip_bfloat16* __restrict__ Vb,
    const float* __restrict__ x,
    const float* __restrict__ gamma,
    float* __restrict__ out)
{
    // carve: K 4x2KB | V 4x2x4KB | P 4x4KB | lsum 1KB
    __shared__ __align__(16) char smem[8192 + 32768 + 16384 + 1024];
    const int t  = threadIdx.x;
    const int l  = t & 63;
    const int w  = t >> 6;                       // wave = cg = tile owner
    const int hi = l >> 5;
    const int q  = l & 31;
    const int bx = blockIdx.x;
    const int b  = (bx >> 1) & 3;                // XCD-pair -> one batch
    const int qt = ((bx >> 3) << 1) | (bx & 1);  // 0..63
    const int q0 = qt * 64;
    const int c0 = w * 64;

    const __bf16* Qp = reinterpret_cast<const __bf16*>(Qb) + (size_t)b * NPOS * NDQK;
    const __bf16* Kp = reinterpret_cast<const __bf16*>(Kb) + (size_t)b * (NPOS * 32);
    const __bf16* Vp = reinterpret_cast<const __bf16*>(Vb) + (size_t)b * NC * NPOS;

    const bf16x8 qf00 = *reinterpret_cast<const bf16x8*>(Qp + (size_t)(q0 + q) * NDQK + 8 * hi);
    const bf16x8 qf01 = *reinterpret_cast<const bf16x8*>(Qp + (size_t)(q0 + q) * NDQK + 16 + 8 * hi);
    const bf16x8 qf10 = *reinterpret_cast<const bf16x8*>(Qp + (size_t)(q0 + 32 + q) * NDQK + 8 * hi);
    const bf16x8 qf11 = *reinterpret_cast<const bf16x8*>(Qp + (size_t)(q0 + 32 + q) * NDQK + 16 + 8 * hi);
    // force the compiler's Q-load wait HERE, not inside the loop
    asm volatile("" :: "v"(qf00), "v"(qf01), "v"(qf10), "v"(qf11));

    // LDS pointers
    char* kb_lds = smem + w * 2048;                       // K tile image (2KB)
    char* vb_lds = smem + 8192 + w * 8192;                // 2 x 4KB V buffers
    __bf16* kbuf = reinterpret_cast<__bf16*>(kb_lds);
    __bf16* vbuf = reinterpret_cast<__bf16*>(vb_lds);
    __bf16* plds = reinterpret_cast<__bf16*>(smem + 40960);
    float*  lsum = reinterpret_cast<float*>(smem + 57344);

    // global DMA sources (per-lane)
    const __bf16* ksrc = Kp + (size_t)w * 1024 + l * 8;   // my tile = 4r+w
    const __bf16* vsrc = Vp + (size_t)w * 2048 + l * 8;   // my cg slice

    #define DMA16(dst, src) __builtin_amdgcn_global_load_lds( \
        (glb_ptr_t)(const char*)(src), (lds_ptr_t)(dst), 16, 0, 0)
    #define DMAK(tp) do { DMA16(kb_lds, (tp)); DMA16(kb_lds + 1024, (tp) + 512); } while (0)
    #define DMAV(bi, tp) do {                                   \
        DMA16(vb_lds + (bi) * 4096,        (tp));               \
        DMA16(vb_lds + (bi) * 4096 + 1024, (tp) + 512);         \
        DMA16(vb_lds + (bi) * 4096 + 2048, (tp) + 1024);        \
        DMA16(vb_lds + (bi) * 4096 + 3072, (tp) + 1536);        \
    } while (0)

    f32x16 acc00, acc01, acc10, acc11;
    #pragma unroll
    for (int r = 0; r < 16; ++r) { acc00[r] = 0.f; acc01[r] = 0.f; acc10[r] = 0.f; acc11[r] = 0.f; }
    float lp0 = 0.f, lp1 = 0.f;

    f32x16 z16;
    #pragma unroll
    for (int r = 0; r < 16; ++r) z16[r] = 0.f;

    auto PV = [&](int tt, const __bf16* vf) {
        const bf16x8 vc0 = *reinterpret_cast<const bf16x8*>(vf);
        const bf16x8 vc1 = *reinterpret_cast<const bf16x8*>(vf + 512);
        const bf16x8 vc2 = *reinterpret_cast<const bf16x8*>(vf + 1024);
        const bf16x8 vc3 = *reinterpret_cast<const bf16x8*>(vf + 1536);
        const __bf16* pf = plds + tt * 2048 + l * 8;
        const bf16x8 pa00 = *reinterpret_cast<const bf16x8*>(pf);
        const bf16x8 pa01 = *reinterpret_cast<const bf16x8*>(pf + 512);
        const bf16x8 pa10 = *reinterpret_cast<const bf16x8*>(pf + 1024);
        const bf16x8 pa11 = *reinterpret_cast<const bf16x8*>(pf + 1536);
        acc00 = __builtin_amdgcn_mfma_f32_32x32x16_bf16(vc0, pa00, acc00, 0, 0, 0);
        acc00 = __builtin_amdgcn_mfma_f32_32x32x16_bf16(vc1, pa01, acc00, 0, 0, 0);
        acc01 = __builtin_amdgcn_mfma_f32_32x32x16_bf16(vc2, pa00, acc01, 0, 0, 0);
        acc01 = __builtin_amdgcn_mfma_f32_32x32x16_bf16(vc3, pa01, acc01, 0, 0, 0);
        acc10 = __builtin_amdgcn_mfma_f32_32x32x16_bf16(vc0, pa10, acc10, 0, 0, 0);
        acc10 = __builtin_amdgcn_mfma_f32_32x32x16_bf16(vc1, pa11, acc10, 0, 0, 0);
        acc11 = __builtin_amdgcn_mfma_f32_32x32x16_bf16(vc2, pa10, acc11, 0, 0, 0);
        acc11 = __builtin_amdgcn_mfma_f32_32x32x16_bf16(vc3, pa11, acc11, 0, 0, 0);
    };

    // prologue: K(tile w) + V(tile 0 -> buf0); outstanding = 6
    DMAK(ksrc);
    DMAV(0, vsrc);

    #pragma unroll 1
    for (int r = 0; r < 32; ++r) {
        // ---- QK phase: K DMA retired at vmcnt(4) (V t0 stays in flight)
        asm volatile("s_waitcnt vmcnt(4)" ::: "memory");
        __builtin_amdgcn_sched_barrier(0);
        {
            const bf16x8 kc0 = *reinterpret_cast<const bf16x8*>(kbuf + l * 8);
            const bf16x8 kc1 = *reinterpret_cast<const bf16x8*>(kbuf + 512 + l * 8);
            f32x16 s0 = __builtin_amdgcn_mfma_f32_32x32x16_bf16(kc0, qf00, z16, 0, 0, 0);
            s0 = __builtin_amdgcn_mfma_f32_32x32x16_bf16(kc1, qf01, s0, 0, 0, 0);
            f32x16 s1 = __builtin_amdgcn_mfma_f32_32x32x16_bf16(kc0, qf10, z16, 0, 0, 0);
            s1 = __builtin_amdgcn_mfma_f32_32x32x16_bf16(kc1, qf11, s1, 0, 0, 0);

            float p0[16], p1[16];
            #pragma unroll
            for (int i = 0; i < 16; ++i) p0[i] = __builtin_amdgcn_exp2f(s0[i]);
            #pragma unroll
            for (int i = 0; i < 16; ++i) p1[i] = __builtin_amdgcn_exp2f(s1[i]);

            lp0 += (((p0[0] + p0[1]) + (p0[2] + p0[3])) + ((p0[4] + p0[5]) + (p0[6] + p0[7])))
                 + (((p0[8] + p0[9]) + (p0[10] + p0[11])) + ((p0[12] + p0[13]) + (p0[14] + p0[15])));
            lp1 += (((p1[0] + p1[1]) + (p1[2] + p1[3])) + ((p1[4] + p1[5]) + (p1[6] + p1[7])))
                 + (((p1[8] + p1[9]) + (p1[10] + p1[11])) + ((p1[12] + p1[13]) + (p1[14] + p1[15])));

            bf16x8 pa00, pa01, pa10, pa11;
            #pragma unroll
            for (int i = 0; i < 8; ++i) {
                pa00[i] = (__bf16)p0[i]; pa01[i] = (__bf16)p0[8 + i];
                pa10[i] = (__bf16)p1[i]; pa11[i] = (__bf16)p1[8 + i];
            }
            __bf16* pw = plds + w * 2048 + l * 8;
            *reinterpret_cast<bf16x8*>(pw)        = pa00;
            *reinterpret_cast<bf16x8*>(pw + 512)  = pa01;
            *reinterpret_cast<bf16x8*>(pw + 1024) = pa10;
            *reinterpret_cast<bf16x8*>(pw + 1536) = pa11;
        }
        asm volatile("s_waitcnt lgkmcnt(0)" ::: "memory");
        __builtin_amdgcn_s_barrier();                   // P visible; vmcnt intact
        __builtin_amdgcn_sched_barrier(0);

        // ---- PV phase: tiles 4r+0..3, V double-buffer buf0/buf1
        DMAV(1, vsrc + 1 * 8192);                       // t1 -> buf1 [V0,V1]=8
        asm volatile("s_waitcnt vmcnt(4)" ::: "memory"); // t0 landed
        __builtin_amdgcn_sched_barrier(0);
        PV(0, vbuf + l * 8);

        asm volatile("s_waitcnt lgkmcnt(0)" ::: "memory"); // buf0 reads done
        __builtin_amdgcn_sched_barrier(0);
        DMAV(0, vsrc + 2 * 8192);                       // t2 -> buf0 [V1,V2]=8
        asm volatile("s_waitcnt vmcnt(4)" ::: "memory"); // t1 landed
        __builtin_amdgcn_sched_barrier(0);
        PV(1, vbuf + 2048 + l * 8);

        asm volatile("s_waitcnt lgkmcnt(0)" ::: "memory"); // buf1 reads done
        __builtin_amdgcn_sched_barrier(0);
        DMAV(1, vsrc + 3 * 8192);                       // t3 -> buf1 [V2,V3]=8
        asm volatile("s_waitcnt vmcnt(4)" ::: "memory"); // t2 landed
        __builtin_amdgcn_sched_barrier(0);
        PV(2, vbuf + l * 8);

        asm volatile("s_waitcnt lgkmcnt(0)" ::: "memory"); // buf0 reads done
        __builtin_amdgcn_sched_barrier(0);
        ksrc += 4096;
        vsrc += 4 * 8192;
        if (r < 31) {
            DMAK(ksrc);                                 // next K  [V3,K]=6
            DMAV(0, vsrc);                              // next t0 [V3,K,V0']=10
            asm volatile("s_waitcnt vmcnt(6)" ::: "memory"); // t3 landed
        } else {
            asm volatile("s_waitcnt vmcnt(0)" ::: "memory");
        }
        __builtin_amdgcn_sched_barrier(0);
        PV(3, vbuf + 2048 + l * 8);

        asm volatile("s_waitcnt lgkmcnt(0)" ::: "memory");
        __builtin_amdgcn_s_barrier();                   // P reads done pre-overwrite
        __builtin_amdgcn_sched_barrier(0);
    }
    #undef DMA16
    #undef DMAK
    #undef DMAV

    // ---- epilogue: share l partials (each wave covered 32 of 128 tiles)
    const float lt0 = lp0 + __shfl_xor(lp0, 32);
    const float lt1 = lp1 + __shfl_xor(lp1, 32);
    lsum[w * 64 + 32 * hi + q] = hi ? lt1 : lt0;
    __syncthreads();

    const float gm  = gamma[0];
    const float gl0 = gm / (lsum[q]      + lsum[64 + q]  + lsum[128 + q] + lsum[192 + q]);
    const float gl1 = gm / (lsum[32 + q] + lsum[96 + q]  + lsum[160 + q] + lsum[224 + q]);
    #pragma unroll
    for (int r = 0; r < 16; ++r) {
        const int crow = (r & 3) + 8 * (r >> 2) + 4 * hi;
        const size_t g00 = ((size_t)(b * NC + c0 + crow)) * NPOS + q0 + q;
        const size_t g01 = g00 + (size_t)32 * NPOS;
        out[g00]      = x[g00]      + gl0 * acc00[r];
        out[g01]      = x[g01]      + gl0 * acc01[r];
        out[g00 + 32] = x[g00 + 32] + gl1 * acc10[r];
        out[g01 + 32] = x[g01 + 32] + gl1 * acc11[r];
    }
}

extern "C" void kernel_launch(void* const* d_in, const int* in_sizes, int n_in,
                              void* d_out, int out_size, void* d_ws, size_t ws_size,
                              hipStream_t stream) {
    (void)in_sizes; (void)n_in; (void)out_size; (void)ws_size;
    const float* x     = (const float*)d_in[0];
    const float* Wq    = (const float*)d_in[1];
    const float* bq    = (const float*)d_in[2];
    const float* Wk    = (const float*)d_in[3];
    const float* bk    = (const float*)d_in[4];
    const float* Wv    = (const float*)d_in[5];
    const float* bv    = (const float*)d_in[6];
    const float* gamma = (const float*)d_in[7];
    float* out = (float*)d_out;

    char* ws = (char*)d_ws;
    __hip_bfloat16* Qb = (__hip_bfloat16*)(ws);                    // 1 MB
    __hip_bfloat16* Kb = (__hip_bfloat16*)(ws + (1u << 20));       // 1 MB (K frag-image)
    __hip_bfloat16* Vb = (__hip_bfloat16*)(ws + (2u << 20));       // 8 MB (V frag-image)

    proj_kernel<<<640, 256, 0, stream>>>(x, Wq, bq, Wk, bk, Wv, bv, Qb, Kb, Vb);
    attn_kernel<<<256, 256, 0, stream>>>(Qb, Kb, Vb, x, gamma, out);
}

// Round 19
// 87.093 us; speedup vs baseline: 1.3455x; 1.0559x over previous
//
#include <hip/hip_runtime.h>
#include <hip/hip_bf16.h>

#define NB   4
#define NC   256
#define NPOS 4096
#define NDQK 32

typedef __bf16 bf16x8  __attribute__((ext_vector_type(8)));
typedef float  f32x16  __attribute__((ext_vector_type(16)));

typedef __attribute__((address_space(3))) char*       lds_ptr_t;
typedef const __attribute__((address_space(1))) char* glb_ptr_t;

// V image: [b][jt 128][cg 4][seg 4][hi 2][c' 32][e 8]
// K image: [b][jt 128][seg 2][hi 2][row 32][e 8], row PRE-PERMUTED.
// A tile is contiguous; DMA lane l moves bytes l*16; LDS holds the exact
// fragment image -> all reads at lane*16B, conflict-free by construction.

// =====================================================================
// Projection (unchanged from r18)
// =====================================================================
__global__ __launch_bounds__(256) void proj_kernel(
    const float* __restrict__ x,
    const float* __restrict__ Wq, const float* __restrict__ bq,
    const float* __restrict__ Wk, const float* __restrict__ bk,
    const float* __restrict__ Wv, const float* __restrict__ bv,
    __hip_bfloat16* __restrict__ Qb, __hip_bfloat16* __restrict__ Kb,
    __hip_bfloat16* __restrict__ Vb)
{
    const int t   = threadIdx.x;
    const int l   = t & 63;
    const int w   = t >> 6;
    const int hi  = l >> 5;
    const int col = l & 31;
    const int row = l & 31;

    const int item = blockIdx.x * 4 + w;     // 0..2559
    const int th   = item & 1;
    const int nch  = (item >> 1) & 63;
    const int rest = item >> 7;              // 0..19
    const int g    = rest % 5;
    const int b    = rest / 5;

    const float *W0, *W1, *bs0, *bs1;
    int o0 = 0, o1 = 0;
    if (g < 4) {
        o0 = g * 64; o1 = g * 64 + 32;
        W0 = Wv + (size_t)o0 * NC; W1 = Wv + (size_t)o1 * NC;
        bs0 = bv + o0; bs1 = bv + o1;
    } else {
        W0 = Wq; W1 = Wk; bs0 = bq; bs1 = bk;
    }

    bf16x8 wf0[16], wf1[16];
    const float* Wr0 = W0 + (size_t)row * NC + 8 * hi;
    const float* Wr1 = W1 + (size_t)row * NC + 8 * hi;
    #pragma unroll
    for (int kk = 0; kk < 16; ++kk) {
        float4 a0 = *reinterpret_cast<const float4*>(Wr0 + kk * 16);
        float4 c0 = *reinterpret_cast<const float4*>(Wr0 + kk * 16 + 4);
        float4 a1 = *reinterpret_cast<const float4*>(Wr1 + kk * 16);
        float4 c1 = *reinterpret_cast<const float4*>(Wr1 + kk * 16 + 4);
        bf16x8 f0, f1;
        f0[0] = (__bf16)a0.x; f0[1] = (__bf16)a0.y; f0[2] = (__bf16)a0.z; f0[3] = (__bf16)a0.w;
        f0[4] = (__bf16)c0.x; f0[5] = (__bf16)c0.y; f0[6] = (__bf16)c0.z; f0[7] = (__bf16)c0.w;
        f1[0] = (__bf16)a1.x; f1[1] = (__bf16)a1.y; f1[2] = (__bf16)a1.z; f1[3] = (__bf16)a1.w;
        f1[4] = (__bf16)c1.x; f1[5] = (__bf16)c1.y; f1[6] = (__bf16)c1.z; f1[7] = (__bf16)c1.w;
        wf0[kk] = f0; wf1[kk] = f1;
    }

    const int n0 = nch * 64 + th * 32;
    f32x16 acc0, acc1;
    #pragma unroll
    for (int r = 0; r < 16; ++r) { acc0[r] = 0.f; acc1[r] = 0.f; }

    const float* xcol = x + (size_t)b * NC * NPOS + n0 + col;
    #pragma unroll
    for (int kk = 0; kk < 16; ++kk) {
        bf16x8 bf;
        #pragma unroll
        for (int i = 0; i < 8; ++i)
            bf[i] = (__bf16)xcol[(size_t)(kk * 16 + 8 * hi + i) * NPOS];
        acc0 = __builtin_amdgcn_mfma_f32_32x32x16_bf16(wf0[kk], bf, acc0, 0, 0, 0);
        acc1 = __builtin_amdgcn_mfma_f32_32x32x16_bf16(wf1[kk], bf, acc1, 0, 0, 0);
    }

    if (g < 4) {
        __hip_bfloat16* vt = Vb + (size_t)b * NC * NPOS
                                + (size_t)(n0 >> 5) * 8192 + (size_t)g * 2048
                                + ((col >> 4) << 9) + (((col >> 3) & 1) << 8)
                                + (col & 7);
        #pragma unroll
        for (int r = 0; r < 16; ++r) {
            const int orow = (r & 3) + 8 * (r >> 2) + 4 * hi;
            vt[orow * 8]        = __float2bfloat16(acc0[r] + bs0[orow]);
            vt[1024 + orow * 8] = __float2bfloat16(acc1[r] + bs1[orow]);
        }
    } else {
        #pragma unroll
        for (int r = 0; r < 16; ++r) {
            const int orow = (r & 3) + 8 * (r >> 2) + 4 * hi;
            Qb[((size_t)(b * NPOS) + n0 + col) * NDQK + orow] =
                __float2bfloat16((acc0[r] + bs0[orow]) * 1.44269504088896f);
        }
        const int prow = (col & 0x13) | ((col & 4) << 1) | ((col & 8) >> 1);
        __hip_bfloat16* kt = Kb + (size_t)b * (NPOS * 32)
                                + (size_t)(n0 >> 5) * 1024 + prow * 8;
        #pragma unroll
        for (int r = 0; r < 16; ++r) {
            const int orow = (r & 3) + 8 * (r >> 2) + 4 * hi;
            kt[(orow >> 4) * 512 + ((orow >> 3) & 1) * 256 + (orow & 7)] =
                __float2bfloat16(acc1[r] + bs1[orow]);
        }
    }
}

// =====================================================================
// Fused flash attention + residual, de-dup softmax, fully-pipelined DMA.
//
// Block = 4 waves = 4 cg; grid 256. Per round of 4 j-tiles: wave w does
// QK+softmax for tile 4r+w, shares P via LDS; all waves PV all 4 tiles
// for their cg. V: 4 DEDICATED buffers/wave (buf tt <-> tile tt) -> no
// intra-round reuse, no per-PV lgkm drains; next round's tile tt DMA'd
// right after PV(tt) (its reads are retired: compiler lgkm waits precede
// PV's MFMAs, DMA issued after in program order). K single-buffered,
// prefetched after the mid-barrier. Stationary vmcnt ledger (always 18
// outstanding): QK waits vmcnt(16) [retire K], PV waits vmcnt(14)
// [retire own tile]; tail round peeled with 12/8/4/0. Only DMAs in
// flight — no register loads -> r17's regalloc race class impossible.
// LDS: V 64KB | K 8KB | P 16KB | lsum 1KB = 89KB (1 block/CU).
// =====================================================================
__global__ __launch_bounds__(256, 1) void attn_kernel(
    const __hip_bfloat16* __restrict__ Qb,
    const __hip_bfloat16* __restrict__ Kb,
    const __hip_bfloat16* __restrict__ Vb,
    const float* __restrict__ x,
    const float* __restrict__ gamma,
    float* __restrict__ out)
{
    __shared__ __align__(16) char smem[65536 + 8192 + 16384 + 1024];
    const int t  = threadIdx.x;
    const int l  = t & 63;
    const int w  = t >> 6;                       // wave = cg = tile owner
    const int hi = l >> 5;
    const int q  = l & 31;
    const int bx = blockIdx.x;
    const int b  = (bx >> 1) & 3;                // XCD-pair -> one batch
    const int qt = ((bx >> 3) << 1) | (bx & 1);  // 0..63
    const int q0 = qt * 64;
    const int c0 = w * 64;

    const __bf16* Qp = reinterpret_cast<const __bf16*>(Qb) + (size_t)b * NPOS * NDQK;
    const __bf16* Kp = reinterpret_cast<const __bf16*>(Kb) + (size_t)b * (NPOS * 32);
    const __bf16* Vp = reinterpret_cast<const __bf16*>(Vb) + (size_t)b * NC * NPOS;

    const bf16x8 qf00 = *reinterpret_cast<const bf16x8*>(Qp + (size_t)(q0 + q) * NDQK + 8 * hi);
    const bf16x8 qf01 = *reinterpret_cast<const bf16x8*>(Qp + (size_t)(q0 + q) * NDQK + 16 + 8 * hi);
    const bf16x8 qf10 = *reinterpret_cast<const bf16x8*>(Qp + (size_t)(q0 + 32 + q) * NDQK + 8 * hi);
    const bf16x8 qf11 = *reinterpret_cast<const bf16x8*>(Qp + (size_t)(q0 + 32 + q) * NDQK + 16 + 8 * hi);
    asm volatile("" :: "v"(qf00), "v"(qf01), "v"(qf10), "v"(qf11));  // Q wait here

    char*   vb_lds = smem + w * 16384;                    // 4 x 4KB dedicated bufs
    char*   kb_lds = smem + 65536 + w * 2048;             // K tile (2KB)
    __bf16* vbuf   = reinterpret_cast<__bf16*>(vb_lds);
    __bf16* kbuf   = reinterpret_cast<__bf16*>(kb_lds);
    __bf16* plds   = reinterpret_cast<__bf16*>(smem + 73728);
    float*  lsum   = reinterpret_cast<float*>(smem + 90112);

    const __bf16* ksrc = Kp + (size_t)w * 1024 + l * 8;   // my tile = 4r+w
    const __bf16* vsrc = Vp + (size_t)w * 2048 + l * 8;   // my cg slice

    #define DMA16(dst, src) __builtin_amdgcn_global_load_lds( \
        (glb_ptr_t)(const char*)(src), (lds_ptr_t)(dst), 16, 0, 0)
    #define DMAK(tp) do { DMA16(kb_lds, (tp)); DMA16(kb_lds + 1024, (tp) + 512); } while (0)
    #define DMAV1(bi, tp) do {                                  \
        DMA16(vb_lds + (bi) * 4096,        (tp));               \
        DMA16(vb_lds + (bi) * 4096 + 1024, (tp) + 512);         \
        DMA16(vb_lds + (bi) * 4096 + 2048, (tp) + 1024);        \
        DMA16(vb_lds + (bi) * 4096 + 3072, (tp) + 1536);        \
    } while (0)

    f32x16 acc00, acc01, acc10, acc11;
    #pragma unroll
    for (int r = 0; r < 16; ++r) { acc00[r] = 0.f; acc01[r] = 0.f; acc10[r] = 0.f; acc11[r] = 0.f; }
    float lp0 = 0.f, lp1 = 0.f;

    f32x16 z16;
    #pragma unroll
    for (int r = 0; r < 16; ++r) z16[r] = 0.f;

    auto QK = [&]() {
        const bf16x8 kc0 = *reinterpret_cast<const bf16x8*>(kbuf + l * 8);
        const bf16x8 kc1 = *reinterpret_cast<const bf16x8*>(kbuf + 512 + l * 8);
        f32x16 s0 = __builtin_amdgcn_mfma_f32_32x32x16_bf16(kc0, qf00, z16, 0, 0, 0);
        s0 = __builtin_amdgcn_mfma_f32_32x32x16_bf16(kc1, qf01, s0, 0, 0, 0);
        f32x16 s1 = __builtin_amdgcn_mfma_f32_32x32x16_bf16(kc0, qf10, z16, 0, 0, 0);
        s1 = __builtin_amdgcn_mfma_f32_32x32x16_bf16(kc1, qf11, s1, 0, 0, 0);

        float p0[16], p1[16];
        #pragma unroll
        for (int i = 0; i < 16; ++i) p0[i] = __builtin_amdgcn_exp2f(s0[i]);
        #pragma unroll
        for (int i = 0; i < 16; ++i) p1[i] = __builtin_amdgcn_exp2f(s1[i]);

        lp0 += (((p0[0] + p0[1]) + (p0[2] + p0[3])) + ((p0[4] + p0[5]) + (p0[6] + p0[7])))
             + (((p0[8] + p0[9]) + (p0[10] + p0[11])) + ((p0[12] + p0[13]) + (p0[14] + p0[15])));
        lp1 += (((p1[0] + p1[1]) + (p1[2] + p1[3])) + ((p1[4] + p1[5]) + (p1[6] + p1[7])))
             + (((p1[8] + p1[9]) + (p1[10] + p1[11])) + ((p1[12] + p1[13]) + (p1[14] + p1[15])));

        bf16x8 pa00, pa01, pa10, pa11;
        #pragma unroll
        for (int i = 0; i < 8; ++i) {
            pa00[i] = (__bf16)p0[i]; pa01[i] = (__bf16)p0[8 + i];
            pa10[i] = (__bf16)p1[i]; pa11[i] = (__bf16)p1[8 + i];
        }
        __bf16* pw = plds + w * 2048 + l * 8;
        *reinterpret_cast<bf16x8*>(pw)        = pa00;
        *reinterpret_cast<bf16x8*>(pw + 512)  = pa01;
        *reinterpret_cast<bf16x8*>(pw + 1024) = pa10;
        *reinterpret_cast<bf16x8*>(pw + 1536) = pa11;
    };

    auto PV = [&](int tt) {
        const __bf16* vf = vbuf + tt * 2048 + l * 8;
        const bf16x8 vc0 = *reinterpret_cast<const bf16x8*>(vf);
        const bf16x8 vc1 = *reinterpret_cast<const bf16x8*>(vf + 512);
        const bf16x8 vc2 = *reinterpret_cast<const bf16x8*>(vf + 1024);
        const bf16x8 vc3 = *reinterpret_cast<const bf16x8*>(vf + 1536);
        const __bf16* pf = plds + tt * 2048 + l * 8;
        const bf16x8 pa00 = *reinterpret_cast<const bf16x8*>(pf);
        const bf16x8 pa01 = *reinterpret_cast<const bf16x8*>(pf + 512);
        const bf16x8 pa10 = *reinterpret_cast<const bf16x8*>(pf + 1024);
        const bf16x8 pa11 = *reinterpret_cast<const bf16x8*>(pf + 1536);
        acc00 = __builtin_amdgcn_mfma_f32_32x32x16_bf16(vc0, pa00, acc00, 0, 0, 0);
        acc00 = __builtin_amdgcn_mfma_f32_32x32x16_bf16(vc1, pa01, acc00, 0, 0, 0);
        acc01 = __builtin_amdgcn_mfma_f32_32x32x16_bf16(vc2, pa00, acc01, 0, 0, 0);
        acc01 = __builtin_amdgcn_mfma_f32_32x32x16_bf16(vc3, pa01, acc01, 0, 0, 0);
        acc10 = __builtin_amdgcn_mfma_f32_32x32x16_bf16(vc0, pa10, acc10, 0, 0, 0);
        acc10 = __builtin_amdgcn_mfma_f32_32x32x16_bf16(vc1, pa11, acc10, 0, 0, 0);
        acc11 = __builtin_amdgcn_mfma_f32_32x32x16_bf16(vc2, pa10, acc11, 0, 0, 0);
        acc11 = __builtin_amdgcn_mfma_f32_32x32x16_bf16(vc3, pa11, acc11, 0, 0, 0);
    };

    #define WAIT(n) do { asm volatile("s_waitcnt vmcnt(" #n ")" ::: "memory"); \
                         __builtin_amdgcn_sched_barrier(0); } while (0)
    #define FENCE()  __builtin_amdgcn_sched_barrier(0)
    #define MIDBAR() do { asm volatile("s_waitcnt lgkmcnt(0)" ::: "memory"); \
                          __builtin_amdgcn_s_barrier(); FENCE(); } while (0)

    // prologue: K0 (oldest) + V tiles 0..3 of round 0 -> 18 outstanding
    DMAK(ksrc);
    DMAV1(0, vsrc);
    DMAV1(1, vsrc + 8192);
    DMAV1(2, vsrc + 2 * 8192);
    DMAV1(3, vsrc + 3 * 8192);

    #pragma unroll 1
    for (int r = 0; r < 31; ++r) {
        WAIT(16);                        // K_r landed (V_r 16 in flight)
        QK();
        MIDBAR();                        // P visible; K reads drained

        ksrc += 4096;                    // K buffer free -> prefetch K_{r+1}
        DMAK(ksrc);
        FENCE();

        const __bf16* vnext = vsrc + 4 * 8192;
        WAIT(14);  PV(0);  FENCE();  DMAV1(0, vnext);             FENCE();
        WAIT(14);  PV(1);  FENCE();  DMAV1(1, vnext + 8192);      FENCE();
        WAIT(14);  PV(2);  FENCE();  DMAV1(2, vnext + 2 * 8192);  FENCE();
        WAIT(14);  PV(3);  FENCE();  DMAV1(3, vnext + 3 * 8192);  FENCE();
        vsrc = vnext;

        MIDBAR();                        // all LDS reads drained; P overwrite safe
    }
    // ---- tail round 31: nothing new issued
    WAIT(16);
    QK();
    MIDBAR();
    WAIT(12);  PV(0);
    WAIT(8);   PV(1);
    WAIT(4);   PV(2);
    WAIT(0);   PV(3);

    #undef DMA16
    #undef DMAK
    #undef DMAV1
    #undef WAIT
    #undef FENCE
    #undef MIDBAR

    // ---- epilogue: share l partials (each wave covered 32 of 128 tiles)
    const float lt0 = lp0 + __shfl_xor(lp0, 32);
    const float lt1 = lp1 + __shfl_xor(lp1, 32);
    lsum[w * 64 + 32 * hi + q] = hi ? lt1 : lt0;
    __syncthreads();

    const float gm  = gamma[0];
    const float gl0 = gm / (lsum[q]      + lsum[64 + q]  + lsum[128 + q] + lsum[192 + q]);
    const float gl1 = gm / (lsum[32 + q] + lsum[96 + q]  + lsum[160 + q] + lsum[224 + q]);
    #pragma unroll
    for (int r = 0; r < 16; ++r) {
        const int crow = (r & 3) + 8 * (r >> 2) + 4 * hi;
        const size_t g00 = ((size_t)(b * NC + c0 + crow)) * NPOS + q0 + q;
        const size_t g01 = g00 + (size_t)32 * NPOS;
        out[g00]      = x[g00]      + gl0 * acc00[r];
        out[g01]      = x[g01]      + gl0 * acc01[r];
        out[g00 + 32] = x[g00 + 32] + gl1 * acc10[r];
        out[g01 + 32] = x[g01 + 32] + gl1 * acc11[r];
    }
}

extern "C" void kernel_launch(void* const* d_in, const int* in_sizes, int n_in,
                              void* d_out, int out_size, void* d_ws, size_t ws_size,
                              hipStream_t stream) {
    (void)in_sizes; (void)n_in; (void)out_size; (void)ws_size;
    const float* x     = (const float*)d_in[0];
    const float* Wq    = (const float*)d_in[1];
    const float* bq    = (const float*)d_in[2];
    const float* Wk    = (const float*)d_in[3];
    const float* bk    = (const float*)d_in[4];
    const float* Wv    = (const float*)d_in[5];
    const float* bv    = (const float*)d_in[6];
    const float* gamma = (const float*)d_in[7];
    float* out = (float*)d_out;

    char* ws = (char*)d_ws;
    __hip_bfloat16* Qb = (__hip_bfloat16*)(ws);                    // 1 MB
    __hip_bfloat16* Kb = (__hip_bfloat16*)(ws + (1u << 20));       // 1 MB (K frag-image)
    __hip_bfloat16* Vb = (__hip_bfloat16*)(ws + (2u << 20));       // 8 MB (V frag-image)

    proj_kernel<<<640, 256, 0, stream>>>(x, Wq, bq, Wk, bk, Wv, bv, Qb, Kb, Vb);
    attn_kernel<<<256, 256, 0, stream>>>(Qb, Kb, Vb, x, gamma, out);
}